// Round 10
// baseline (523.765 us; speedup 1.0000x reference)
//
#include <hip/hip_runtime.h>
#include <hip/hip_bf16.h>

#define DEVB 64
#define LSEQ 512
#define DDIM 600

typedef short short8 __attribute__((ext_vector_type(8)));
typedef float f32x4 __attribute__((ext_vector_type(4)));
typedef _Float16 f16x8 __attribute__((ext_vector_type(8)));
typedef _Float16 f16x4 __attribute__((ext_vector_type(4)));

constexpr int LDP = 40;   // padded stride for fallback-wsum tiles (16B-aligned rows)

__device__ __forceinline__ unsigned short f2bf(float x) {
    union { float f; unsigned u; } v; v.f = x;
    unsigned r = v.u + 0x7fffu + ((v.u >> 16) & 1u);   // RNE
    return (unsigned short)(r >> 16);
}
__device__ __forceinline__ f32x4 mfma16(short8 a, short8 b, f32x4 c) {
    return __builtin_amdgcn_mfma_f32_16x16x32_bf16(a, b, c, 0, 0, 0);
}
__device__ __forceinline__ f32x4 mfma16h(f16x8 a, f16x8 b, f32x4 c) {
    return __builtin_amdgcn_mfma_f32_16x16x32_f16(a, b, c, 0, 0, 0);
}

// ---------------------------------------------------------------------------
// K0: transcvt2 — XT[b][d][r] = fp16(X[b][r][d]) for X in {P, H}, one grid.
//     Tile 64r x 64d via LDS. Pure transpose+convert.
// ---------------------------------------------------------------------------
__global__ __launch_bounds__(256) void transcvt2(
    const float* __restrict__ P, const float* __restrict__ H,
    _Float16* __restrict__ pT, _Float16* __restrict__ hT)
{
    int blk = blockIdx.x;
    const float* X; _Float16* XT;
    if (blk < DEVB * 80) { X = P; XT = pT; }
    else { blk -= DEVB * 80; X = H; XT = hT; }

    int b   = blk / 80;
    int rem = blk % 80;
    int r0  = (rem / 10) << 6;
    int d0  = (rem % 10) << 6;
    const float* Xb = X + (size_t)b * LSEQ * DDIM;

    __shared__ _Float16 T[64 * 66];
    int t = threadIdx.x;
#pragma unroll
    for (int it = 0; it < 2; ++it) {
        int g  = t + (it << 8);
        int ri = g >> 3;           // 0..63
        int dc = (g & 7) << 3;     // 0..56
        if (d0 + dc < DDIM) {      // 8-chunks fully valid or fully invalid (600%8==0)
            const float* src = Xb + (size_t)(r0 + ri) * DDIM + d0 + dc;
            float4 x0 = *(const float4*)src;
            float4 x1 = *(const float4*)(src + 4);
            float xf[8] = {x0.x, x0.y, x0.z, x0.w, x1.x, x1.y, x1.z, x1.w};
#pragma unroll
            for (int j = 0; j < 8; ++j)
                T[(dc + j) * 66 + ri] = (_Float16)xf[j];
        }
    }
    __syncthreads();

    int d  = t >> 2;
    int ch = (t & 3) << 4;
    if (d0 + d < DDIM) {
        unsigned buf[8];
#pragma unroll
        for (int i = 0; i < 8; ++i)
            buf[i] = *(const unsigned*)&T[d * 66 + ch + 2 * i];
        unsigned* dst = (unsigned*)(XT + ((size_t)b * DDIM + d0 + d) * LSEQ + r0 + ch);
        *(uint4*)(dst)     = *(uint4*)&buf[0];
        *(uint4*)(dst + 4) = *(uint4*)&buf[4];
    }
}

// ---------------------------------------------------------------------------
// K1: attn[b][p][h] = sum_d P[b][p][d] * H[b][h][d]   (fp32 out)
// 512 threads / 8 waves, tile 128(P, hi+lo) x 256(H, hi). Reads fp32 directly;
// fp16 split in the LDS-write phase. LDS 64 KB dbuf -> 2 blocks/CU = 16 waves.
// Chunk-XOR swizzle on (row>>1)&3 (0 bank conflicts, verified R9).
// ---------------------------------------------------------------------------
__global__ __launch_bounds__(512, 4) void attn_gemm(
    const float* __restrict__ P, const float* __restrict__ H,
    float* __restrict__ attn)
{
    const int bid = blockIdx.x;
    const int swz = (bid & 7) * 64 + (bid >> 3);   // 512 blocks, 8 XCDs, bijective
    const int b  = swz >> 3;
    const int pt = ((swz >> 1) & 3) << 7;          // 4 tiles of 128
    const int ht = (swz & 1) << 8;                 // 2 tiles of 256
    const float* Pb = P + ((size_t)b * LSEQ + pt) * DDIM;
    const float* Hb = H + ((size_t)b * LSEQ + ht) * DDIM;
    float* Ab = attn + (size_t)b * LSEQ * LSEQ;

    __shared__ _Float16 Ah[2][128 * 32], Al[2][128 * 32], Bh[2][256 * 32];

    const int t    = threadIdx.x;
    const int lane = t & 63;
    const int wave = t >> 6;                 // 0..7
    const int wm = (wave >> 2) << 6;         // {0,64}
    const int wn = (wave & 3) << 6;          // {0,64,128,192}
    const int fr = lane & 15;
    const int fq = lane >> 4;
    const int srow = t >> 2;                 // 0..127
    const int sc8  = (t & 3) << 3;           // logical col chunk base (8 elems)

    // physical chunk = logical chunk XOR ((row>>1)&3); invariant under row+128,
    // equals (fr>>1)&3 on the read side -> conflict-free (verified R9).
    const int wchunk = (t & 3) ^ ((srow >> 1) & 3);
    const int woff   = srow * 32 + (wchunk << 3);
    const int rcoff  = ((fq ^ ((fr >> 1) & 3)) << 3);

    float4 pf[6];
    const float4 fz = {0.f, 0.f, 0.f, 0.f};
    auto issue = [&](int k0) {
        bool ok = (k0 + sc8) < DDIM;   // zero the 600..607 tail chunk
        size_t offA  = (size_t)srow * DDIM + k0 + sc8;
        size_t offB1 = (size_t)(srow + 128) * DDIM + k0 + sc8;
        if (ok) {
            pf[0] = *(const float4*)(Pb + offA);
            pf[1] = *(const float4*)(Pb + offA + 4);
            pf[2] = *(const float4*)(Hb + offA);
            pf[3] = *(const float4*)(Hb + offA + 4);
            pf[4] = *(const float4*)(Hb + offB1);
            pf[5] = *(const float4*)(Hb + offB1 + 4);
        } else {
            pf[0] = fz; pf[1] = fz; pf[2] = fz;
            pf[3] = fz; pf[4] = fz; pf[5] = fz;
        }
    };
    auto wr = [&](int buf) {
        {   // A: P row srow, hi+lo
            float af[8] = {pf[0].x, pf[0].y, pf[0].z, pf[0].w,
                           pf[1].x, pf[1].y, pf[1].z, pf[1].w};
            f16x8 hi, lo;
#pragma unroll
            for (int j = 0; j < 8; ++j) {
                hi[j] = (_Float16)af[j];
                lo[j] = (_Float16)(af[j] - (float)hi[j]);
            }
            *(f16x8*)&Ah[buf][woff] = hi;
            *(f16x8*)&Al[buf][woff] = lo;
        }
        {   // B: H rows srow and srow+128, hi only
            float h0[8] = {pf[2].x, pf[2].y, pf[2].z, pf[2].w,
                           pf[3].x, pf[3].y, pf[3].z, pf[3].w};
            float h1[8] = {pf[4].x, pf[4].y, pf[4].z, pf[4].w,
                           pf[5].x, pf[5].y, pf[5].z, pf[5].w};
            f16x8 b0, b1;
#pragma unroll
            for (int j = 0; j < 8; ++j) {
                b0[j] = (_Float16)h0[j];
                b1[j] = (_Float16)h1[j];
            }
            *(f16x8*)&Bh[buf][woff] = b0;
            *(f16x8*)&Bh[buf][woff + 128 * 32] = b1;
        }
    };

    issue(0);
    wr(0);
    issue(32);
    __syncthreads();

    f32x4 acc[4][4];
#pragma unroll
    for (int i = 0; i < 4; ++i)
#pragma unroll
        for (int j = 0; j < 4; ++j) acc[i][j] = (f32x4){0.f, 0.f, 0.f, 0.f};

    constexpr int NK = 19;   // ceil(600/32)
    int cur = 0;
    for (int it = 0; it < NK; ++it) {
        f16x8 ah[4], al[4], bh[4];
#pragma unroll
        for (int i = 0; i < 4; ++i) {
            int ra = (wm + (i << 4) + fr) * 32 + rcoff;
            int rb = (wn + (i << 4) + fr) * 32 + rcoff;
            ah[i] = *(const f16x8*)&Ah[cur][ra];
            al[i] = *(const f16x8*)&Al[cur][ra];
            bh[i] = *(const f16x8*)&Bh[cur][rb];
        }
        if (it + 1 < NK) {
            wr(cur ^ 1);                       // cvt + stage tile it+1
            if (it + 2 < NK) issue((it + 2) << 5);
        }
#pragma unroll
        for (int mi = 0; mi < 4; ++mi)
#pragma unroll
            for (int ni = 0; ni < 4; ++ni) {
                f32x4 c = acc[mi][ni];
                c = mfma16h(ah[mi], bh[ni], c);
                c = mfma16h(al[mi], bh[ni], c);
                acc[mi][ni] = c;
            }
        __syncthreads();
        cur ^= 1;
    }

#pragma unroll
    for (int mi = 0; mi < 4; ++mi)
#pragma unroll
        for (int ni = 0; ni < 4; ++ni)
#pragma unroll
            for (int j = 0; j < 4; ++j) {
                int p = pt + wm + (mi << 4) + (fq << 2) + j;
                int h = ht + wn + (ni << 4) + fr;
                Ab[(size_t)p * LSEQ + h] = acc[mi][ni][j];
            }
}

// ---------------------------------------------------------------------------
// K2: stats_w1 — ONE pass over attn per 64-row stripe:
//   per-row (over h): M1, R1, W1 fp16 (hm-masked softmax)
//   per-col partials (over p, pm-masked online): Mp/Tp/Sp [b][8][512]
// ---------------------------------------------------------------------------
__global__ __launch_bounds__(256) void stats_w1(
    const float* __restrict__ attn, const float* __restrict__ hmask,
    const float* __restrict__ pmask,
    float* __restrict__ M1, float* __restrict__ R1,
    _Float16* __restrict__ W1,
    float* __restrict__ Mp, float* __restrict__ Tp, float* __restrict__ Sp)
{
    int b      = blockIdx.x >> 3;
    int stripe = blockIdx.x & 7;
    int lane   = threadIdx.x & 63;
    int wave   = threadIdx.x >> 6;
    const float* hm = hmask + (b << 9);
    const float* pm = pmask + (b << 9);

    float4 m0 = *(const float4*)(hm + (lane << 3));
    float4 m1 = *(const float4*)(hm + (lane << 3) + 4);
    float mk[8] = {m0.x, m0.y, m0.z, m0.w, m1.x, m1.y, m1.z, m1.w};

    float cM[8], cT[8], cS[8];
#pragma unroll
    for (int j = 0; j < 8; ++j) { cM[j] = -1e30f; cT[j] = 0.f; cS[j] = 0.f; }

    for (int i = 0; i < 16; ++i) {
        int row   = (stripe << 6) + (wave << 4) + i;
        int rowid = (b << 9) + row;
        const float* rp = attn + (size_t)rowid * LSEQ + (lane << 3);
        float4 s0 = *(const float4*)rp;
        float4 s1 = *(const float4*)(rp + 4);
        float s[8] = {s0.x, s0.y, s0.z, s0.w, s1.x, s1.y, s1.z, s1.w};

        float v[8];
#pragma unroll
        for (int j = 0; j < 8; ++j) v[j] = s[j] * mk[j];
        float mx = -1e30f;
#pragma unroll
        for (int j = 0; j < 8; ++j) mx = fmaxf(mx, v[j]);
#pragma unroll
        for (int off = 32; off; off >>= 1) mx = fmaxf(mx, __shfl_xor(mx, off));

        float e[8], T = 0.f, S = 0.f;
#pragma unroll
        for (int j = 0; j < 8; ++j) { e[j] = __expf(v[j] - mx); T += mk[j] * e[j]; S += e[j]; }
#pragma unroll
        for (int off = 32; off; off >>= 1) { T += __shfl_xor(T, off); S += __shfl_xor(S, off); }
        float R = 1.f / (T + 1e-13f * S);

        if (W1) {
            union { f16x8 v8; _Float16 h[8]; } wv;
#pragma unroll
            for (int j = 0; j < 8; ++j) wv.h[j] = (_Float16)(mk[j] * e[j] * R);
            *(f16x8*)(W1 + (size_t)rowid * LSEQ + (lane << 3)) = wv.v8;
        }
        if (lane == 0) { M1[rowid] = mx; R1[rowid] = R; }

        float pmv = pm[row];
#pragma unroll
        for (int j = 0; j < 8; ++j) {
            float v2 = s[j] * pmv;
            float nm = fmaxf(cM[j], v2);
            float sc = __expf(cM[j] - nm);
            float e2 = __expf(v2 - nm);
            cT[j] = cT[j] * sc + pmv * e2;
            cS[j] = cS[j] * sc + e2;
            cM[j] = nm;
        }
    }

    __shared__ float LM[4][512], LT[4][512], LS[4][512];
#pragma unroll
    for (int j = 0; j < 8; ++j) {
        int c = (lane << 3) + j;
        LM[wave][c] = cM[j]; LT[wave][c] = cT[j]; LS[wave][c] = cS[j];
    }
    __syncthreads();

    size_t base = (size_t)((b << 3) + stripe) * 512;
    for (int cc = threadIdx.x; cc < 512; cc += 256) {
        float gm = fmaxf(fmaxf(LM[0][cc], LM[1][cc]), fmaxf(LM[2][cc], LM[3][cc]));
        float gT = 0.f, gS = 0.f;
#pragma unroll
        for (int w = 0; w < 4; ++w) {
            float sc = __expf(LM[w][cc] - gm);
            gT += LT[w][cc] * sc;
            gS += LS[w][cc] * sc;
        }
        Mp[base + cc] = gm; Tp[base + cc] = gT; Sp[base + cc] = gS;
    }
}

// ---------------------------------------------------------------------------
// K3 (fallback only): col_merge — merge 8 stripe partials -> M2, R2
// ---------------------------------------------------------------------------
__global__ __launch_bounds__(256) void col_merge(
    const float* __restrict__ Mp, const float* __restrict__ Tp,
    const float* __restrict__ Sp, float* __restrict__ M2, float* __restrict__ R2)
{
    int b = blockIdx.x >> 1;
    int c = ((blockIdx.x & 1) << 8) + threadIdx.x;
    float gm = -1e30f, gT = 0.f, gS = 0.f;
#pragma unroll
    for (int st = 0; st < 8; ++st) {
        size_t idx = (size_t)((b << 3) + st) * 512 + c;
        float m = Mp[idx], tt = Tp[idx], ss = Sp[idx];
        float nm  = fmaxf(gm, m);
        float sc1 = __expf(gm - nm), sc2 = __expf(m - nm);
        gT = gT * sc1 + tt * sc2;
        gS = gS * sc1 + ss * sc2;
        gm = nm;
    }
    M2[(b << 9) + c] = gm;
    R2[(b << 9) + c] = 1.f / (gT + 1e-13f * gS);
}

// ---------------------------------------------------------------------------
// K4: w2gen_m — per-block 8-stripe merge (from Mp/Tp/Sp) then
//   W2[b][h][p] = pm[p] ? exp(attn[b][p][h]-M2[h])*R2[h] : 0 (fp16)
//   via LDS tile transpose. Tile = 64p x 128h.
// ---------------------------------------------------------------------------
__global__ __launch_bounds__(256) void w2gen_m(
    const float* __restrict__ attn, const float* __restrict__ pmask,
    const float* __restrict__ Mp, const float* __restrict__ Tp,
    const float* __restrict__ Sp, _Float16* __restrict__ W2)
{
    int blk = blockIdx.x;
    int b  = blk >> 5;
    int p0 = ((blk >> 2) & 7) << 6;
    int h0 = (blk & 3) << 7;
    const float* Ab = attn + (size_t)b * LSEQ * LSEQ;
    const float* pm = pmask + (b << 9);

    __shared__ float sM[128], sR[128];
    __shared__ _Float16 T[128 * 66];
    int t = threadIdx.x;
    if (t < 128) {
        float gm = -1e30f, gT = 0.f, gS = 0.f;
#pragma unroll
        for (int st = 0; st < 8; ++st) {
            size_t idx = (size_t)((b << 3) + st) * 512 + h0 + t;
            float m = Mp[idx], tt = Tp[idx], ss = Sp[idx];
            float nm  = fmaxf(gm, m);
            float sc1 = __expf(gm - nm), sc2 = __expf(m - nm);
            gT = gT * sc1 + tt * sc2;
            gS = gS * sc1 + ss * sc2;
            gm = nm;
        }
        sM[t] = gm;
        sR[t] = 1.f / (gT + 1e-13f * gS);
    }
    __syncthreads();

#pragma unroll
    for (int it = 0; it < 8; ++it) {
        int g  = t + (it << 8);
        int pi = g >> 5;           // 0..63
        int hc = (g & 31) << 2;    // 0..124
        float4 x = *(const float4*)(Ab + (size_t)(p0 + pi) * LSEQ + h0 + hc);
        float pv = pm[p0 + pi];
        _Float16 w0 = 0, w1 = 0, w2 = 0, w3 = 0;
        if (pv != 0.f) {
            w0 = (_Float16)(__expf(x.x - sM[hc + 0]) * sR[hc + 0]);
            w1 = (_Float16)(__expf(x.y - sM[hc + 1]) * sR[hc + 1]);
            w2 = (_Float16)(__expf(x.z - sM[hc + 2]) * sR[hc + 2]);
            w3 = (_Float16)(__expf(x.w - sM[hc + 3]) * sR[hc + 3]);
        }
        T[(hc + 0) * 66 + pi] = w0;
        T[(hc + 1) * 66 + pi] = w1;
        T[(hc + 2) * 66 + pi] = w2;
        T[(hc + 3) * 66 + pi] = w3;
    }
    __syncthreads();

    int h  = t >> 1;
    int po = (t & 1) << 5;
    unsigned buf[16];
#pragma unroll
    for (int i = 0; i < 16; ++i)
        buf[i] = *(const unsigned*)&T[h * 66 + po + 2 * i];
    unsigned* dst = (unsigned*)(W2 + ((size_t)(b << 9) + h0 + h) * LSEQ + p0 + po);
#pragma unroll
    for (int i = 0; i < 4; ++i)
        *(uint4*)(dst + 4 * i) = *(uint4*)&buf[4 * i];
}

// ---------------------------------------------------------------------------
// K5: out[b][m][d] = mask_m[m] * sum_k W[b][m][k] * BT[b][d][k]   (fp16 MFMA)
//     LDS [128][32] chunk-XOR swizzle keyed on (row>>1)&3 -> 32 KB.
// ---------------------------------------------------------------------------
__global__ __launch_bounds__(256) void gemm_fp16(
    const _Float16* __restrict__ W, const _Float16* __restrict__ BT,
    const float* __restrict__ mask_m, float* __restrict__ out)
{
    const int bid = blockIdx.x;
    const int swz = (bid & 7) * 160 + (bid >> 3);   // 1280 blocks, 8 XCDs
    const int b   = swz / 20;
    const int rem = swz % 20;
    const int m0  = (rem / 5) << 7;
    const int n0  = (rem % 5) << 7;
    const _Float16* Wb = W  + (size_t)b * LSEQ * LSEQ;
    const _Float16* Bb = BT + (size_t)b * DDIM * LSEQ;

    __shared__ _Float16 Wl[2][128 * 32];
    __shared__ _Float16 Bl[2][128 * 32];

    const int t    = threadIdx.x;
    const int lane = t & 63;
    const int wave = t >> 6;
    const int wm = (wave >> 1) << 6;
    const int wn = (wave & 1) << 6;
    const int fr = lane & 15;
    const int fq = lane >> 4;
    const int srow = t >> 2;
    const int sc8  = (t & 3) << 3;

    const int wchunk = (t & 3) ^ ((srow >> 1) & 3);
    const int woff   = srow * 32 + (wchunk << 3);
    const int rcoff  = ((fq ^ ((fr >> 1) & 3)) << 3);

    f16x8 pw[2], pb[2];
    const f16x8 zz = {0, 0, 0, 0, 0, 0, 0, 0};
    auto issue = [&](int k0) {
#pragma unroll
        for (int r = 0; r < 2; ++r) {
            int row = srow + (r << 6);
            pw[r] = *(const f16x8*)(Wb + (size_t)(m0 + row) * LSEQ + k0 + sc8);
            int nrow = n0 + row;
            pb[r] = (nrow < DDIM) ? *(const f16x8*)(Bb + (size_t)nrow * LSEQ + k0 + sc8) : zz;
        }
    };
    auto wr = [&](int buf) {
#pragma unroll
        for (int r = 0; r < 2; ++r) {
            int off = woff + (r << 11);
            *(f16x8*)&Wl[buf][off] = pw[r];
            *(f16x8*)&Bl[buf][off] = pb[r];
        }
    };

    issue(0);
    wr(0);
    issue(32);
    __syncthreads();

    f32x4 acc[4][4];
#pragma unroll
    for (int i = 0; i < 4; ++i)
#pragma unroll
        for (int j = 0; j < 4; ++j) acc[i][j] = (f32x4){0.f, 0.f, 0.f, 0.f};

    constexpr int NK = 16;   // 512/32
    int cur = 0;
    for (int it = 0; it < NK; ++it) {
        f16x8 af[4], bfr[4];
#pragma unroll
        for (int i = 0; i < 4; ++i) {
            af[i]  = *(const f16x8*)&Wl[cur][(wm + (i << 4) + fr) * 32 + rcoff];
            bfr[i] = *(const f16x8*)&Bl[cur][(wn + (i << 4) + fr) * 32 + rcoff];
        }
        if (it + 1 < NK) {
            wr(cur ^ 1);
            if (it + 2 < NK) issue((it + 2) << 5);
        }
#pragma unroll
        for (int mi = 0; mi < 4; ++mi)
#pragma unroll
            for (int ni = 0; ni < 4; ++ni)
                acc[mi][ni] = mfma16h(af[mi], bfr[ni], acc[mi][ni]);
        __syncthreads();
        cur ^= 1;
    }

    const float* mmb = mask_m + (b << 9) + m0;
#pragma unroll
    for (int mi = 0; mi < 4; ++mi)
#pragma unroll
        for (int j = 0; j < 4; ++j) {
            int row = wm + (mi << 4) + (fq << 2) + j;
            float mm = mmb[row];
#pragma unroll
            for (int ni = 0; ni < 4; ++ni) {
                int d = n0 + wn + (ni << 4) + fr;
                if (d < DDIM)
                    out[((size_t)(b << 9) + m0 + row) * DDIM + d] = mm * acc[mi][ni][j];
            }
        }
}

// ---------------------------------------------------------------------------
// Fallback wsum (round-1 style) — only if ws_size too small for fast path
// ---------------------------------------------------------------------------
template <int TRANSA>
__global__ __launch_bounds__(256) void wsum(
    const float* __restrict__ attn, const float* __restrict__ Bsrc,
    const float* __restrict__ mask_k, const float* __restrict__ mask_m,
    const float* __restrict__ Mst, const float* __restrict__ Rst,
    float* __restrict__ out)
{
    const int blk = blockIdx.x;
    const int b   = blk / 20;
    const int rem = blk % 20;
    const int m0  = (rem / 5) << 7;
    const int n0  = (rem % 5) << 7;

    const float* Ab  = attn + (size_t)b * LSEQ * LSEQ;
    const float* Bb  = Bsrc + (size_t)b * LSEQ * DDIM;
    const float* mkb = mask_k + (b << 9);

    __shared__ unsigned short Wl[128 * LDP];
    __shared__ unsigned short Bl[128 * LDP];
    __shared__ float Ml[128], Rl[128], Mm[128];

    const int t    = threadIdx.x;
    const int lane = t & 63;
    const int wave = t >> 6;
    const int wm = (wave >> 1) << 6;
    const int wn = (wave & 1) << 6;
    const int fr = lane & 15;
    const int fq = lane >> 4;

    if (t < 128) {
        Ml[t] = Mst[(b << 9) + m0 + t];
        Rl[t] = Rst[(b << 9) + m0 + t];
        Mm[t] = mask_m[(b << 9) + m0 + t];
    }
    __syncthreads();

    f32x4 acc[4][4];
#pragma unroll
    for (int i = 0; i < 4; ++i)
#pragma unroll
        for (int j = 0; j < 4; ++j) acc[i][j] = (f32x4){0.f, 0.f, 0.f, 0.f};

    for (int k0 = 0; k0 < LSEQ; k0 += 32) {
        if constexpr (TRANSA == 0) {
#pragma unroll
            for (int r = 0; r < 4; ++r) {
                int idx = t + (r << 8);
                int row = idx >> 3;
                int c4  = (idx & 7) << 2;
                float4 x  = *(const float4*)(Ab + (size_t)(m0 + row) * LSEQ + k0 + c4);
                float4 km = *(const float4*)(mkb + k0 + c4);
                float Mv = Ml[row], Rv = Rl[row];
                ushort4 w;
                w.x = (km.x != 0.f) ? f2bf(__expf(x.x - Mv) * Rv) : (unsigned short)0;
                w.y = (km.y != 0.f) ? f2bf(__expf(x.y - Mv) * Rv) : (unsigned short)0;
                w.z = (km.z != 0.f) ? f2bf(__expf(x.z - Mv) * Rv) : (unsigned short)0;
                w.w = (km.w != 0.f) ? f2bf(__expf(x.w - Mv) * Rv) : (unsigned short)0;
                *(ushort4*)&Wl[row * LDP + c4] = w;
            }
        } else {
#pragma unroll
            for (int r = 0; r < 4; ++r) {
                int mh = t & 127;
                int pq = (t >> 7) + (r << 1);
                float Mv = Ml[mh], Rv = Rl[mh];
                ushort4 w;
#pragma unroll
                for (int j = 0; j < 4; ++j) {
                    int k = k0 + (pq << 2) + j;
                    float x  = Ab[(size_t)k * LSEQ + m0 + mh];
                    float km = mkb[k];
                    ((unsigned short*)&w)[j] =
                        (km != 0.f) ? f2bf(__expf(x - Mv) * Rv) : (unsigned short)0;
                }
                *(ushort4*)&Wl[mh * LDP + (pq << 2)] = w;
            }
        }
#pragma unroll
        for (int r = 0; r < 4; ++r) {
            int d  = t & 127;
            int kq = (t >> 7) + (r << 1);
            bool valid = (n0 + d) < DDIM;
            ushort4 v;
#pragma unroll
            for (int j = 0; j < 4; ++j) {
                int k = k0 + (kq << 2) + j;
                float x = valid ? Bb[(size_t)k * DDIM + n0 + d] : 0.f;
                ((unsigned short*)&v)[j] = f2bf(x);
            }
            *(ushort4*)&Bl[d * LDP + (kq << 2)] = v;
        }
        __syncthreads();

        short8 af[4], bfr[4];
#pragma unroll
        for (int i = 0; i < 4; ++i) {
            af[i]  = *(const short8*)&Wl[(wm + (i << 4) + fr) * LDP + (fq << 3)];
            bfr[i] = *(const short8*)&Bl[(wn + (i << 4) + fr) * LDP + (fq << 3)];
        }
#pragma unroll
        for (int mi = 0; mi < 4; ++mi)
#pragma unroll
            for (int ni = 0; ni < 4; ++ni)
                acc[mi][ni] = mfma16(af[mi], bfr[ni], acc[mi][ni]);
        __syncthreads();
    }

#pragma unroll
    for (int mi = 0; mi < 4; ++mi)
#pragma unroll
        for (int j = 0; j < 4; ++j) {
            int row = wm + (mi << 4) + (fq << 2) + j;
            float mm = Mm[row];
#pragma unroll
            for (int ni = 0; ni < 4; ++ni) {
                int d = n0 + wn + (ni << 4) + fr;
                if (d < DDIM)
                    out[((size_t)(b << 9) + m0 + row) * DDIM + d] = mm * acc[mi][ni][j];
            }
        }
}

// ---------------------------------------------------------------------------
extern "C" void kernel_launch(void* const* d_in, const int* in_sizes, int n_in,
                              void* d_out, int out_size, void* d_ws, size_t ws_size,
                              hipStream_t stream)
{
    const float* P  = (const float*)d_in[0];   // encoded_premise   [64,512,600]
    const float* pm = (const float*)d_in[1];   // premise_mask      [64,512]
    const float* H  = (const float*)d_in[2];   // encoded_hypothesis[64,512,600]
    const float* hm = (const float*)d_in[3];   // hypothesis_mask   [64,512]
    float* out = (float*)d_out;
    char* o  = (char*)d_out;
    char* ws = (char*)d_ws;

    const size_t E = (size_t)DEVB * LSEQ * DDIM;   // 19,660,800 out-elems per half

    // d_out scratch layout (upper half only; dead before gemms write):
    //   hT [78,643,200 : 117,964,800) fp16 | W1 [117,964,800 : 151,519,232) fp16
    //   gemm<0> writes out[0 : 78.6M) while reading hT/W1 — disjoint.
    //   gemm<1> writes out[78.6M : 157.3M) reading only ws (W2/pT) — hT/W1 dead.
    _Float16* hT = (_Float16*)(o + 78643200);
    _Float16* W1 = (_Float16*)(o + 117964800);

    // ws layout (fast path):
    //   attn fp32 [0 : 67.11M) | pT [67.11 : 106.43M) | W2 [106.43 : 139.98M)
    //   Mp/Tp/Sp [139.98 : 143.13M) | M1/R1 [143.13 : 143.65M)
    const size_t fast_need = 143654912;

    if (ws_size >= fast_need) {
        float*     attn = (float*)ws;
        _Float16*  pT   = (_Float16*)(ws + 67108864);
        _Float16*  W2   = (_Float16*)(ws + 67108864 + 39321600);
        float*     Mp   = (float*)(ws + 139984896);
        float*     Tp   = Mp + (size_t)DEVB * 8 * 512;
        float*     Sp   = Tp + (size_t)DEVB * 8 * 512;
        float*     M1   = Sp + (size_t)DEVB * 8 * 512;
        float*     R1   = M1 + DEVB * LSEQ;

        transcvt2<<<DEVB * 160, 256, 0, stream>>>(P, H, pT, hT);
        attn_gemm<<<DEVB * 8, 512, 0, stream>>>(P, H, attn);
        stats_w1<<<DEVB * 8, 256, 0, stream>>>(attn, hm, pm, M1, R1, W1, Mp, Tp, Sp);
        w2gen_m<<<DEVB * 32, 256, 0, stream>>>(attn, pm, Mp, Tp, Sp, W2);
        gemm_fp16<<<DEVB * 20, 256, 0, stream>>>(W1, hT, pm, out);
        gemm_fp16<<<DEVB * 20, 256, 0, stream>>>(W2, pT, hm, out + E);
    } else {
        // fallback: attn + partials + stats = 70.78 MB of ws; no prep needed
        float* attn = (float*)ws;
        float* Mp   = (float*)(ws + 67108864);
        float* Tp   = Mp + (size_t)DEVB * 8 * 512;
        float* Sp   = Tp + (size_t)DEVB * 8 * 512;
        float* M1   = Sp + (size_t)DEVB * 8 * 512;
        float* R1   = M1 + DEVB * LSEQ;
        float* M2   = R1 + DEVB * LSEQ;
        float* R2   = M2 + DEVB * LSEQ;

        attn_gemm<<<DEVB * 8, 512, 0, stream>>>(P, H, attn);
        stats_w1<<<DEVB * 8, 256, 0, stream>>>(attn, hm, pm, M1, R1, nullptr, Mp, Tp, Sp);
        col_merge<<<DEVB * 2, 256, 0, stream>>>(Mp, Tp, Sp, M2, R2);
        wsum<0><<<DEVB * 20, 256, 0, stream>>>(attn, H, hm, pm, M1, R1, out);
        wsum<1><<<DEVB * 20, 256, 0, stream>>>(attn, P, pm, hm, M2, R2, out + E);
    }
}

// Round 11
// 330.244 us; speedup vs baseline: 1.5860x; 1.5860x over previous
//
#include <hip/hip_runtime.h>
#include <hip/hip_bf16.h>

#define DEVB 64
#define LSEQ 512
#define DDIM 600

typedef short short8 __attribute__((ext_vector_type(8)));
typedef float f32x4 __attribute__((ext_vector_type(4)));
typedef _Float16 f16x8 __attribute__((ext_vector_type(8)));
typedef _Float16 f16x4 __attribute__((ext_vector_type(4)));

constexpr int LDP = 40;   // padded stride for fallback-wsum tiles (16B-aligned rows)

__device__ __forceinline__ unsigned short f2bf(float x) {
    union { float f; unsigned u; } v; v.f = x;
    unsigned r = v.u + 0x7fffu + ((v.u >> 16) & 1u);   // RNE
    return (unsigned short)(r >> 16);
}
__device__ __forceinline__ f32x4 mfma16(short8 a, short8 b, f32x4 c) {
    return __builtin_amdgcn_mfma_f32_16x16x32_bf16(a, b, c, 0, 0, 0);
}
__device__ __forceinline__ f32x4 mfma16h(f16x8 a, f16x8 b, f32x4 c) {
    return __builtin_amdgcn_mfma_f32_16x16x32_f16(a, b, c, 0, 0, 0);
}

// ---------------------------------------------------------------------------
// K0: transcvt2 — XT[b][d][r] = fp16(X[b][r][d]) for X in {P, H}, one grid.
//     Tile 64r x 64d via LDS. Pure transpose+convert.
// ---------------------------------------------------------------------------
__global__ __launch_bounds__(256) void transcvt2(
    const float* __restrict__ P, const float* __restrict__ H,
    _Float16* __restrict__ pT, _Float16* __restrict__ hT)
{
    int blk = blockIdx.x;
    const float* X; _Float16* XT;
    if (blk < DEVB * 80) { X = P; XT = pT; }
    else { blk -= DEVB * 80; X = H; XT = hT; }

    int b   = blk / 80;
    int rem = blk % 80;
    int r0  = (rem / 10) << 6;
    int d0  = (rem % 10) << 6;
    const float* Xb = X + (size_t)b * LSEQ * DDIM;

    __shared__ _Float16 T[64 * 66];
    int t = threadIdx.x;
#pragma unroll
    for (int it = 0; it < 2; ++it) {
        int g  = t + (it << 8);
        int ri = g >> 3;           // 0..63
        int dc = (g & 7) << 3;     // 0..56
        if (d0 + dc < DDIM) {      // 8-chunks fully valid or fully invalid (600%8==0)
            const float* src = Xb + (size_t)(r0 + ri) * DDIM + d0 + dc;
            float4 x0 = *(const float4*)src;
            float4 x1 = *(const float4*)(src + 4);
            float xf[8] = {x0.x, x0.y, x0.z, x0.w, x1.x, x1.y, x1.z, x1.w};
#pragma unroll
            for (int j = 0; j < 8; ++j)
                T[(dc + j) * 66 + ri] = (_Float16)xf[j];
        }
    }
    __syncthreads();

    int d  = t >> 2;
    int ch = (t & 3) << 4;
    if (d0 + d < DDIM) {
        unsigned buf[8];
#pragma unroll
        for (int i = 0; i < 8; ++i)
            buf[i] = *(const unsigned*)&T[d * 66 + ch + 2 * i];
        unsigned* dst = (unsigned*)(XT + ((size_t)b * DDIM + d0 + d) * LSEQ + r0 + ch);
        *(uint4*)(dst)     = *(uint4*)&buf[0];
        *(uint4*)(dst + 4) = *(uint4*)&buf[4];
    }
}

// ---------------------------------------------------------------------------
// K1: attn[b][p][h] = sum_d P[b][p][d] * H[b][h][d]   (fp32 out)
// 512 threads / 8 waves, tile 128(P, hi+lo) x 256(H, hi). Reads fp32 directly;
// fp16 split in the LDS-write phase. LDS 64 KB dbuf -> 2 blocks/CU = 16 waves.
// NOTE: __launch_bounds__(512) ONLY — a second arg of 4 made hipcc cap VGPRs
// at 64 and spill the whole accumulator to scratch (R10: 709 MB WRITE_SIZE).
// ---------------------------------------------------------------------------
__global__ __launch_bounds__(512) void attn_gemm(
    const float* __restrict__ P, const float* __restrict__ H,
    float* __restrict__ attn)
{
    const int bid = blockIdx.x;
    const int swz = (bid & 7) * 64 + (bid >> 3);   // 512 blocks, 8 XCDs, bijective
    const int b  = swz >> 3;
    const int pt = ((swz >> 1) & 3) << 7;          // 4 tiles of 128
    const int ht = (swz & 1) << 8;                 // 2 tiles of 256
    const float* Pb = P + ((size_t)b * LSEQ + pt) * DDIM;
    const float* Hb = H + ((size_t)b * LSEQ + ht) * DDIM;
    float* Ab = attn + (size_t)b * LSEQ * LSEQ;

    __shared__ _Float16 Ah[2][128 * 32], Al[2][128 * 32], Bh[2][256 * 32];

    const int t    = threadIdx.x;
    const int lane = t & 63;
    const int wave = t >> 6;                 // 0..7
    const int wm = (wave >> 2) << 6;         // {0,64}
    const int wn = (wave & 3) << 6;          // {0,64,128,192}
    const int fr = lane & 15;
    const int fq = lane >> 4;
    const int srow = t >> 2;                 // 0..127
    const int sc8  = (t & 3) << 3;           // logical col chunk base (8 elems)

    // physical chunk = logical chunk XOR ((row>>1)&3); invariant under row+128,
    // equals (fr>>1)&3 on the read side -> conflict-free (verified R9).
    const int wchunk = (t & 3) ^ ((srow >> 1) & 3);
    const int woff   = srow * 32 + (wchunk << 3);
    const int rcoff  = ((fq ^ ((fr >> 1) & 3)) << 3);

    float4 pf[6];
    const float4 fz = {0.f, 0.f, 0.f, 0.f};
    auto issue = [&](int k0) {
        bool ok = (k0 + sc8) < DDIM;   // zero the 600..607 tail chunk
        size_t offA  = (size_t)srow * DDIM + k0 + sc8;
        size_t offB1 = (size_t)(srow + 128) * DDIM + k0 + sc8;
        if (ok) {
            pf[0] = *(const float4*)(Pb + offA);
            pf[1] = *(const float4*)(Pb + offA + 4);
            pf[2] = *(const float4*)(Hb + offA);
            pf[3] = *(const float4*)(Hb + offA + 4);
            pf[4] = *(const float4*)(Hb + offB1);
            pf[5] = *(const float4*)(Hb + offB1 + 4);
        } else {
            pf[0] = fz; pf[1] = fz; pf[2] = fz;
            pf[3] = fz; pf[4] = fz; pf[5] = fz;
        }
    };
    auto wr = [&](int buf) {
        {   // A: P row srow, hi+lo
            float af[8] = {pf[0].x, pf[0].y, pf[0].z, pf[0].w,
                           pf[1].x, pf[1].y, pf[1].z, pf[1].w};
            f16x8 hi, lo;
#pragma unroll
            for (int j = 0; j < 8; ++j) {
                hi[j] = (_Float16)af[j];
                lo[j] = (_Float16)(af[j] - (float)hi[j]);
            }
            *(f16x8*)&Ah[buf][woff] = hi;
            *(f16x8*)&Al[buf][woff] = lo;
        }
        {   // B: H rows srow and srow+128, hi only
            float h0[8] = {pf[2].x, pf[2].y, pf[2].z, pf[2].w,
                           pf[3].x, pf[3].y, pf[3].z, pf[3].w};
            float h1[8] = {pf[4].x, pf[4].y, pf[4].z, pf[4].w,
                           pf[5].x, pf[5].y, pf[5].z, pf[5].w};
            f16x8 b0, b1;
#pragma unroll
            for (int j = 0; j < 8; ++j) {
                b0[j] = (_Float16)h0[j];
                b1[j] = (_Float16)h1[j];
            }
            *(f16x8*)&Bh[buf][woff] = b0;
            *(f16x8*)&Bh[buf][woff + 128 * 32] = b1;
        }
    };

    issue(0);
    wr(0);
    issue(32);
    __syncthreads();

    f32x4 acc[4][4];
#pragma unroll
    for (int i = 0; i < 4; ++i)
#pragma unroll
        for (int j = 0; j < 4; ++j) acc[i][j] = (f32x4){0.f, 0.f, 0.f, 0.f};

    constexpr int NK = 19;   // ceil(600/32)
    int cur = 0;
    for (int it = 0; it < NK; ++it) {
        f16x8 ah[4], al[4], bh[4];
#pragma unroll
        for (int i = 0; i < 4; ++i) {
            int ra = (wm + (i << 4) + fr) * 32 + rcoff;
            int rb = (wn + (i << 4) + fr) * 32 + rcoff;
            ah[i] = *(const f16x8*)&Ah[cur][ra];
            al[i] = *(const f16x8*)&Al[cur][ra];
            bh[i] = *(const f16x8*)&Bh[cur][rb];
        }
        if (it + 1 < NK) {
            wr(cur ^ 1);                       // cvt + stage tile it+1
            if (it + 2 < NK) issue((it + 2) << 5);
        }
#pragma unroll
        for (int mi = 0; mi < 4; ++mi)
#pragma unroll
            for (int ni = 0; ni < 4; ++ni) {
                f32x4 c = acc[mi][ni];
                c = mfma16h(ah[mi], bh[ni], c);
                c = mfma16h(al[mi], bh[ni], c);
                acc[mi][ni] = c;
            }
        __syncthreads();
        cur ^= 1;
    }

#pragma unroll
    for (int mi = 0; mi < 4; ++mi)
#pragma unroll
        for (int ni = 0; ni < 4; ++ni)
#pragma unroll
            for (int j = 0; j < 4; ++j) {
                int p = pt + wm + (mi << 4) + (fq << 2) + j;
                int h = ht + wn + (ni << 4) + fr;
                Ab[(size_t)p * LSEQ + h] = acc[mi][ni][j];
            }
}

// ---------------------------------------------------------------------------
// K2: stats_w1 — ONE pass over attn per 64-row stripe:
//   per-row (over h): M1, R1, W1 fp16 (hm-masked softmax)
//   per-col partials (over p, pm-masked online): Mp/Tp/Sp [b][8][512]
// ---------------------------------------------------------------------------
__global__ __launch_bounds__(256) void stats_w1(
    const float* __restrict__ attn, const float* __restrict__ hmask,
    const float* __restrict__ pmask,
    float* __restrict__ M1, float* __restrict__ R1,
    _Float16* __restrict__ W1,
    float* __restrict__ Mp, float* __restrict__ Tp, float* __restrict__ Sp)
{
    int b      = blockIdx.x >> 3;
    int stripe = blockIdx.x & 7;
    int lane   = threadIdx.x & 63;
    int wave   = threadIdx.x >> 6;
    const float* hm = hmask + (b << 9);
    const float* pm = pmask + (b << 9);

    float4 m0 = *(const float4*)(hm + (lane << 3));
    float4 m1 = *(const float4*)(hm + (lane << 3) + 4);
    float mk[8] = {m0.x, m0.y, m0.z, m0.w, m1.x, m1.y, m1.z, m1.w};

    float cM[8], cT[8], cS[8];
#pragma unroll
    for (int j = 0; j < 8; ++j) { cM[j] = -1e30f; cT[j] = 0.f; cS[j] = 0.f; }

    for (int i = 0; i < 16; ++i) {
        int row   = (stripe << 6) + (wave << 4) + i;
        int rowid = (b << 9) + row;
        const float* rp = attn + (size_t)rowid * LSEQ + (lane << 3);
        float4 s0 = *(const float4*)rp;
        float4 s1 = *(const float4*)(rp + 4);
        float s[8] = {s0.x, s0.y, s0.z, s0.w, s1.x, s1.y, s1.z, s1.w};

        float v[8];
#pragma unroll
        for (int j = 0; j < 8; ++j) v[j] = s[j] * mk[j];
        float mx = -1e30f;
#pragma unroll
        for (int j = 0; j < 8; ++j) mx = fmaxf(mx, v[j]);
#pragma unroll
        for (int off = 32; off; off >>= 1) mx = fmaxf(mx, __shfl_xor(mx, off));

        float e[8], T = 0.f, S = 0.f;
#pragma unroll
        for (int j = 0; j < 8; ++j) { e[j] = __expf(v[j] - mx); T += mk[j] * e[j]; S += e[j]; }
#pragma unroll
        for (int off = 32; off; off >>= 1) { T += __shfl_xor(T, off); S += __shfl_xor(S, off); }
        float R = 1.f / (T + 1e-13f * S);

        if (W1) {
            union { f16x8 v8; _Float16 h[8]; } wv;
#pragma unroll
            for (int j = 0; j < 8; ++j) wv.h[j] = (_Float16)(mk[j] * e[j] * R);
            *(f16x8*)(W1 + (size_t)rowid * LSEQ + (lane << 3)) = wv.v8;
        }
        if (lane == 0) { M1[rowid] = mx; R1[rowid] = R; }

        float pmv = pm[row];
#pragma unroll
        for (int j = 0; j < 8; ++j) {
            float v2 = s[j] * pmv;
            float nm = fmaxf(cM[j], v2);
            float sc = __expf(cM[j] - nm);
            float e2 = __expf(v2 - nm);
            cT[j] = cT[j] * sc + pmv * e2;
            cS[j] = cS[j] * sc + e2;
            cM[j] = nm;
        }
    }

    __shared__ float LM[4][512], LT[4][512], LS[4][512];
#pragma unroll
    for (int j = 0; j < 8; ++j) {
        int c = (lane << 3) + j;
        LM[wave][c] = cM[j]; LT[wave][c] = cT[j]; LS[wave][c] = cS[j];
    }
    __syncthreads();

    size_t base = (size_t)((b << 3) + stripe) * 512;
    for (int cc = threadIdx.x; cc < 512; cc += 256) {
        float gm = fmaxf(fmaxf(LM[0][cc], LM[1][cc]), fmaxf(LM[2][cc], LM[3][cc]));
        float gT = 0.f, gS = 0.f;
#pragma unroll
        for (int w = 0; w < 4; ++w) {
            float sc = __expf(LM[w][cc] - gm);
            gT += LT[w][cc] * sc;
            gS += LS[w][cc] * sc;
        }
        Mp[base + cc] = gm; Tp[base + cc] = gT; Sp[base + cc] = gS;
    }
}

// ---------------------------------------------------------------------------
// K3 (fallback only): col_merge — merge 8 stripe partials -> M2, R2
// ---------------------------------------------------------------------------
__global__ __launch_bounds__(256) void col_merge(
    const float* __restrict__ Mp, const float* __restrict__ Tp,
    const float* __restrict__ Sp, float* __restrict__ M2, float* __restrict__ R2)
{
    int b = blockIdx.x >> 1;
    int c = ((blockIdx.x & 1) << 8) + threadIdx.x;
    float gm = -1e30f, gT = 0.f, gS = 0.f;
#pragma unroll
    for (int st = 0; st < 8; ++st) {
        size_t idx = (size_t)((b << 3) + st) * 512 + c;
        float m = Mp[idx], tt = Tp[idx], ss = Sp[idx];
        float nm  = fmaxf(gm, m);
        float sc1 = __expf(gm - nm), sc2 = __expf(m - nm);
        gT = gT * sc1 + tt * sc2;
        gS = gS * sc1 + ss * sc2;
        gm = nm;
    }
    M2[(b << 9) + c] = gm;
    R2[(b << 9) + c] = 1.f / (gT + 1e-13f * gS);
}

// ---------------------------------------------------------------------------
// K4: w2gen_m — per-block 8-stripe merge (from Mp/Tp/Sp) then
//   W2[b][h][p] = pm[p] ? exp(attn[b][p][h]-M2[h])*R2[h] : 0 (fp16)
//   via LDS tile transpose. Tile = 64p x 128h.
// ---------------------------------------------------------------------------
__global__ __launch_bounds__(256) void w2gen_m(
    const float* __restrict__ attn, const float* __restrict__ pmask,
    const float* __restrict__ Mp, const float* __restrict__ Tp,
    const float* __restrict__ Sp, _Float16* __restrict__ W2)
{
    int blk = blockIdx.x;
    int b  = blk >> 5;
    int p0 = ((blk >> 2) & 7) << 6;
    int h0 = (blk & 3) << 7;
    const float* Ab = attn + (size_t)b * LSEQ * LSEQ;
    const float* pm = pmask + (b << 9);

    __shared__ float sM[128], sR[128];
    __shared__ _Float16 T[128 * 66];
    int t = threadIdx.x;
    if (t < 128) {
        float gm = -1e30f, gT = 0.f, gS = 0.f;
#pragma unroll
        for (int st = 0; st < 8; ++st) {
            size_t idx = (size_t)((b << 3) + st) * 512 + h0 + t;
            float m = Mp[idx], tt = Tp[idx], ss = Sp[idx];
            float nm  = fmaxf(gm, m);
            float sc1 = __expf(gm - nm), sc2 = __expf(m - nm);
            gT = gT * sc1 + tt * sc2;
            gS = gS * sc1 + ss * sc2;
            gm = nm;
        }
        sM[t] = gm;
        sR[t] = 1.f / (gT + 1e-13f * gS);
    }
    __syncthreads();

#pragma unroll
    for (int it = 0; it < 8; ++it) {
        int g  = t + (it << 8);
        int pi = g >> 5;           // 0..63
        int hc = (g & 31) << 2;    // 0..124
        float4 x = *(const float4*)(Ab + (size_t)(p0 + pi) * LSEQ + h0 + hc);
        float pv = pm[p0 + pi];
        _Float16 w0 = 0, w1 = 0, w2 = 0, w3 = 0;
        if (pv != 0.f) {
            w0 = (_Float16)(__expf(x.x - sM[hc + 0]) * sR[hc + 0]);
            w1 = (_Float16)(__expf(x.y - sM[hc + 1]) * sR[hc + 1]);
            w2 = (_Float16)(__expf(x.z - sM[hc + 2]) * sR[hc + 2]);
            w3 = (_Float16)(__expf(x.w - sM[hc + 3]) * sR[hc + 3]);
        }
        T[(hc + 0) * 66 + pi] = w0;
        T[(hc + 1) * 66 + pi] = w1;
        T[(hc + 2) * 66 + pi] = w2;
        T[(hc + 3) * 66 + pi] = w3;
    }
    __syncthreads();

    int h  = t >> 1;
    int po = (t & 1) << 5;
    unsigned buf[16];
#pragma unroll
    for (int i = 0; i < 16; ++i)
        buf[i] = *(const unsigned*)&T[h * 66 + po + 2 * i];
    unsigned* dst = (unsigned*)(W2 + ((size_t)(b << 9) + h0 + h) * LSEQ + p0 + po);
#pragma unroll
    for (int i = 0; i < 4; ++i)
        *(uint4*)(dst + 4 * i) = *(uint4*)&buf[4 * i];
}

// ---------------------------------------------------------------------------
// K5: out[b][m][d] = mask_m[m] * sum_k W[b][m][k] * BT[b][d][k]   (fp16 MFMA)
//     LDS [128][32] chunk-XOR swizzle keyed on (row>>1)&3 -> 32 KB.
// ---------------------------------------------------------------------------
__global__ __launch_bounds__(256) void gemm_fp16(
    const _Float16* __restrict__ W, const _Float16* __restrict__ BT,
    const float* __restrict__ mask_m, float* __restrict__ out)
{
    const int bid = blockIdx.x;
    const int swz = (bid & 7) * 160 + (bid >> 3);   // 1280 blocks, 8 XCDs
    const int b   = swz / 20;
    const int rem = swz % 20;
    const int m0  = (rem / 5) << 7;
    const int n0  = (rem % 5) << 7;
    const _Float16* Wb = W  + (size_t)b * LSEQ * LSEQ;
    const _Float16* Bb = BT + (size_t)b * DDIM * LSEQ;

    __shared__ _Float16 Wl[2][128 * 32];
    __shared__ _Float16 Bl[2][128 * 32];

    const int t    = threadIdx.x;
    const int lane = t & 63;
    const int wave = t >> 6;
    const int wm = (wave >> 1) << 6;
    const int wn = (wave & 1) << 6;
    const int fr = lane & 15;
    const int fq = lane >> 4;
    const int srow = t >> 2;
    const int sc8  = (t & 3) << 3;

    const int wchunk = (t & 3) ^ ((srow >> 1) & 3);
    const int woff   = srow * 32 + (wchunk << 3);
    const int rcoff  = ((fq ^ ((fr >> 1) & 3)) << 3);

    f16x8 pw[2], pb[2];
    const f16x8 zz = {0, 0, 0, 0, 0, 0, 0, 0};
    auto issue = [&](int k0) {
#pragma unroll
        for (int r = 0; r < 2; ++r) {
            int row = srow + (r << 6);
            pw[r] = *(const f16x8*)(Wb + (size_t)(m0 + row) * LSEQ + k0 + sc8);
            int nrow = n0 + row;
            pb[r] = (nrow < DDIM) ? *(const f16x8*)(Bb + (size_t)nrow * LSEQ + k0 + sc8) : zz;
        }
    };
    auto wr = [&](int buf) {
#pragma unroll
        for (int r = 0; r < 2; ++r) {
            int off = woff + (r << 11);
            *(f16x8*)&Wl[buf][off] = pw[r];
            *(f16x8*)&Bl[buf][off] = pb[r];
        }
    };

    issue(0);
    wr(0);
    issue(32);
    __syncthreads();

    f32x4 acc[4][4];
#pragma unroll
    for (int i = 0; i < 4; ++i)
#pragma unroll
        for (int j = 0; j < 4; ++j) acc[i][j] = (f32x4){0.f, 0.f, 0.f, 0.f};

    constexpr int NK = 16;   // 512/32
    int cur = 0;
    for (int it = 0; it < NK; ++it) {
        f16x8 af[4], bfr[4];
#pragma unroll
        for (int i = 0; i < 4; ++i) {
            af[i]  = *(const f16x8*)&Wl[cur][(wm + (i << 4) + fr) * 32 + rcoff];
            bfr[i] = *(const f16x8*)&Bl[cur][(wn + (i << 4) + fr) * 32 + rcoff];
        }
        if (it + 1 < NK) {
            wr(cur ^ 1);
            if (it + 2 < NK) issue((it + 2) << 5);
        }
#pragma unroll
        for (int mi = 0; mi < 4; ++mi)
#pragma unroll
            for (int ni = 0; ni < 4; ++ni)
                acc[mi][ni] = mfma16h(af[mi], bfr[ni], acc[mi][ni]);
        __syncthreads();
        cur ^= 1;
    }

    const float* mmb = mask_m + (b << 9) + m0;
#pragma unroll
    for (int mi = 0; mi < 4; ++mi)
#pragma unroll
        for (int j = 0; j < 4; ++j) {
            int row = wm + (mi << 4) + (fq << 2) + j;
            float mm = mmb[row];
#pragma unroll
            for (int ni = 0; ni < 4; ++ni) {
                int d = n0 + wn + (ni << 4) + fr;
                if (d < DDIM)
                    out[((size_t)(b << 9) + m0 + row) * DDIM + d] = mm * acc[mi][ni][j];
            }
        }
}

// ---------------------------------------------------------------------------
// Fallback wsum (round-1 style) — only if ws_size too small for fast path
// ---------------------------------------------------------------------------
template <int TRANSA>
__global__ __launch_bounds__(256) void wsum(
    const float* __restrict__ attn, const float* __restrict__ Bsrc,
    const float* __restrict__ mask_k, const float* __restrict__ mask_m,
    const float* __restrict__ Mst, const float* __restrict__ Rst,
    float* __restrict__ out)
{
    const int blk = blockIdx.x;
    const int b   = blk / 20;
    const int rem = blk % 20;
    const int m0  = (rem / 5) << 7;
    const int n0  = (rem % 5) << 7;

    const float* Ab  = attn + (size_t)b * LSEQ * LSEQ;
    const float* Bb  = Bsrc + (size_t)b * LSEQ * DDIM;
    const float* mkb = mask_k + (b << 9);

    __shared__ unsigned short Wl[128 * LDP];
    __shared__ unsigned short Bl[128 * LDP];
    __shared__ float Ml[128], Rl[128], Mm[128];

    const int t    = threadIdx.x;
    const int lane = t & 63;
    const int wave = t >> 6;
    const int wm = (wave >> 1) << 6;
    const int wn = (wave & 1) << 6;
    const int fr = lane & 15;
    const int fq = lane >> 4;

    if (t < 128) {
        Ml[t] = Mst[(b << 9) + m0 + t];
        Rl[t] = Rst[(b << 9) + m0 + t];
        Mm[t] = mask_m[(b << 9) + m0 + t];
    }
    __syncthreads();

    f32x4 acc[4][4];
#pragma unroll
    for (int i = 0; i < 4; ++i)
#pragma unroll
        for (int j = 0; j < 4; ++j) acc[i][j] = (f32x4){0.f, 0.f, 0.f, 0.f};

    for (int k0 = 0; k0 < LSEQ; k0 += 32) {
        if constexpr (TRANSA == 0) {
#pragma unroll
            for (int r = 0; r < 4; ++r) {
                int idx = t + (r << 8);
                int row = idx >> 3;
                int c4  = (idx & 7) << 2;
                float4 x  = *(const float4*)(Ab + (size_t)(m0 + row) * LSEQ + k0 + c4);
                float4 km = *(const float4*)(mkb + k0 + c4);
                float Mv = Ml[row], Rv = Rl[row];
                ushort4 w;
                w.x = (km.x != 0.f) ? f2bf(__expf(x.x - Mv) * Rv) : (unsigned short)0;
                w.y = (km.y != 0.f) ? f2bf(__expf(x.y - Mv) * Rv) : (unsigned short)0;
                w.z = (km.z != 0.f) ? f2bf(__expf(x.z - Mv) * Rv) : (unsigned short)0;
                w.w = (km.w != 0.f) ? f2bf(__expf(x.w - Mv) * Rv) : (unsigned short)0;
                *(ushort4*)&Wl[row * LDP + c4] = w;
            }
        } else {
#pragma unroll
            for (int r = 0; r < 4; ++r) {
                int mh = t & 127;
                int pq = (t >> 7) + (r << 1);
                float Mv = Ml[mh], Rv = Rl[mh];
                ushort4 w;
#pragma unroll
                for (int j = 0; j < 4; ++j) {
                    int k = k0 + (pq << 2) + j;
                    float x  = Ab[(size_t)k * LSEQ + m0 + mh];
                    float km = mkb[k];
                    ((unsigned short*)&w)[j] =
                        (km != 0.f) ? f2bf(__expf(x - Mv) * Rv) : (unsigned short)0;
                }
                *(ushort4*)&Wl[mh * LDP + (pq << 2)] = w;
            }
        }
#pragma unroll
        for (int r = 0; r < 4; ++r) {
            int d  = t & 127;
            int kq = (t >> 7) + (r << 1);
            bool valid = (n0 + d) < DDIM;
            ushort4 v;
#pragma unroll
            for (int j = 0; j < 4; ++j) {
                int k = k0 + (kq << 2) + j;
                float x = valid ? Bb[(size_t)k * DDIM + n0 + d] : 0.f;
                ((unsigned short*)&v)[j] = f2bf(x);
            }
            *(ushort4*)&Bl[d * LDP + (kq << 2)] = v;
        }
        __syncthreads();

        short8 af[4], bfr[4];
#pragma unroll
        for (int i = 0; i < 4; ++i) {
            af[i]  = *(const short8*)&Wl[(wm + (i << 4) + fr) * LDP + (fq << 3)];
            bfr[i] = *(const short8*)&Bl[(wn + (i << 4) + fr) * LDP + (fq << 3)];
        }
#pragma unroll
        for (int mi = 0; mi < 4; ++mi)
#pragma unroll
            for (int ni = 0; ni < 4; ++ni)
                acc[mi][ni] = mfma16(af[mi], bfr[ni], acc[mi][ni]);
        __syncthreads();
    }

#pragma unroll
    for (int mi = 0; mi < 4; ++mi)
#pragma unroll
        for (int j = 0; j < 4; ++j) {
            int row = wm + (mi << 4) + (fq << 2) + j;
            float mm = Mm[row];
#pragma unroll
            for (int ni = 0; ni < 4; ++ni) {
                int d = n0 + wn + (ni << 4) + fr;
                if (d < DDIM)
                    out[((size_t)(b << 9) + m0 + row) * DDIM + d] = mm * acc[mi][ni][j];
            }
        }
}

// ---------------------------------------------------------------------------
extern "C" void kernel_launch(void* const* d_in, const int* in_sizes, int n_in,
                              void* d_out, int out_size, void* d_ws, size_t ws_size,
                              hipStream_t stream)
{
    const float* P  = (const float*)d_in[0];   // encoded_premise   [64,512,600]
    const float* pm = (const float*)d_in[1];   // premise_mask      [64,512]
    const float* H  = (const float*)d_in[2];   // encoded_hypothesis[64,512,600]
    const float* hm = (const float*)d_in[3];   // hypothesis_mask   [64,512]
    float* out = (float*)d_out;
    char* o  = (char*)d_out;
    char* ws = (char*)d_ws;

    const size_t E = (size_t)DEVB * LSEQ * DDIM;   // 19,660,800 out-elems per half

    // d_out scratch layout (upper half only; dead before gemms write):
    //   hT [78,643,200 : 117,964,800) fp16 | W1 [117,964,800 : 151,519,232) fp16
    //   gemm<0> writes out[0 : 78.6M) while reading hT/W1 — disjoint.
    //   gemm<1> writes out[78.6M : 157.3M) reading only ws (W2/pT) — hT/W1 dead.
    _Float16* hT = (_Float16*)(o + 78643200);
    _Float16* W1 = (_Float16*)(o + 117964800);

    // ws layout (fast path):
    //   attn fp32 [0 : 67.11M) | pT [67.11 : 106.43M) | W2 [106.43 : 139.98M)
    //   Mp/Tp/Sp [139.98 : 143.13M) | M1/R1 [143.13 : 143.65M)
    const size_t fast_need = 143654912;

    if (ws_size >= fast_need) {
        float*     attn = (float*)ws;
        _Float16*  pT   = (_Float16*)(ws + 67108864);
        _Float16*  W2   = (_Float16*)(ws + 67108864 + 39321600);
        float*     Mp   = (float*)(ws + 139984896);
        float*     Tp   = Mp + (size_t)DEVB * 8 * 512;
        float*     Sp   = Tp + (size_t)DEVB * 8 * 512;
        float*     M1   = Sp + (size_t)DEVB * 8 * 512;
        float*     R1   = M1 + DEVB * LSEQ;

        transcvt2<<<DEVB * 160, 256, 0, stream>>>(P, H, pT, hT);
        attn_gemm<<<DEVB * 8, 512, 0, stream>>>(P, H, attn);
        stats_w1<<<DEVB * 8, 256, 0, stream>>>(attn, hm, pm, M1, R1, W1, Mp, Tp, Sp);
        w2gen_m<<<DEVB * 32, 256, 0, stream>>>(attn, pm, Mp, Tp, Sp, W2);
        gemm_fp16<<<DEVB * 20, 256, 0, stream>>>(W1, hT, pm, out);
        gemm_fp16<<<DEVB * 20, 256, 0, stream>>>(W2, pT, hm, out + E);
    } else {
        // fallback: attn + partials + stats = 70.78 MB of ws; no prep needed
        float* attn = (float*)ws;
        float* Mp   = (float*)(ws + 67108864);
        float* Tp   = Mp + (size_t)DEVB * 8 * 512;
        float* Sp   = Tp + (size_t)DEVB * 8 * 512;
        float* M1   = Sp + (size_t)DEVB * 8 * 512;
        float* R1   = M1 + DEVB * LSEQ;
        float* M2   = R1 + DEVB * LSEQ;
        float* R2   = M2 + DEVB * LSEQ;

        attn_gemm<<<DEVB * 8, 512, 0, stream>>>(P, H, attn);
        stats_w1<<<DEVB * 8, 256, 0, stream>>>(attn, hm, pm, M1, R1, nullptr, Mp, Tp, Sp);
        col_merge<<<DEVB * 2, 256, 0, stream>>>(Mp, Tp, Sp, M2, R2);
        wsum<0><<<DEVB * 20, 256, 0, stream>>>(attn, H, hm, pm, M1, R1, out);
        wsum<1><<<DEVB * 20, 256, 0, stream>>>(attn, P, pm, hm, M2, R2, out + E);
    }
}

// Round 12
// 321.394 us; speedup vs baseline: 1.6297x; 1.0275x over previous
//
#include <hip/hip_runtime.h>
#include <hip/hip_bf16.h>

#define DEVB 64
#define LSEQ 512
#define DDIM 600

typedef short short8 __attribute__((ext_vector_type(8)));
typedef float f32x4 __attribute__((ext_vector_type(4)));
typedef _Float16 f16x8 __attribute__((ext_vector_type(8)));
typedef _Float16 f16x4 __attribute__((ext_vector_type(4)));

constexpr int LDP = 40;   // padded stride for fallback-wsum tiles (16B-aligned rows)

__device__ __forceinline__ unsigned short f2bf(float x) {
    union { float f; unsigned u; } v; v.f = x;
    unsigned r = v.u + 0x7fffu + ((v.u >> 16) & 1u);   // RNE
    return (unsigned short)(r >> 16);
}
__device__ __forceinline__ unsigned pk16(float a, float b) {
    union { _Float16 h[2]; unsigned u; } p;
    p.h[0] = (_Float16)a; p.h[1] = (_Float16)b;
    return p.u;
}
__device__ __forceinline__ f32x4 mfma16(short8 a, short8 b, f32x4 c) {
    return __builtin_amdgcn_mfma_f32_16x16x32_bf16(a, b, c, 0, 0, 0);
}
__device__ __forceinline__ f32x4 mfma16h(f16x8 a, f16x8 b, f32x4 c) {
    return __builtin_amdgcn_mfma_f32_16x16x32_f16(a, b, c, 0, 0, 0);
}

// ---------------------------------------------------------------------------
// K0: transcvt3 — XT[b][d][r] = fp16(X[b][r][d]) for X in {P, H}, one grid.
//     64r x 128d strip per block; u32-paired LDS writes (2 rows per thread,
//     b32 ops, 2-way-free banks at stride 33).
// ---------------------------------------------------------------------------
__global__ __launch_bounds__(256) void transcvt3(
    const float* __restrict__ P, const float* __restrict__ H,
    _Float16* __restrict__ pT, _Float16* __restrict__ hT)
{
    int blk = blockIdx.x;
    const float* X; _Float16* XT;
    const int half = DEVB * 40;
    if (blk < half) { X = P; XT = pT; }
    else { blk -= half; X = H; XT = hT; }

    int b   = blk / 40;
    int rem = blk % 40;
    int r0  = (rem / 5) << 6;       // 8 r-tiles of 64
    int d0  = (rem % 5) << 7;       // 5 d-strips of 128
    const float* Xb = X + (size_t)b * LSEQ * DDIM;

    __shared__ unsigned T32[2][64 * 33];
    const int t  = threadIdx.x;
    const int rp = t >> 3;          // 0..31 row-pair
    const int dc = (t & 7) << 3;    // 0..56

#pragma unroll
    for (int ht_ = 0; ht_ < 2; ++ht_) {
        int dd = d0 + (ht_ << 6) + dc;
        if (dd < DDIM) {            // 8-chunks fully valid or invalid (600%8==0)
            const float* s0 = Xb + (size_t)(r0 + 2 * rp) * DDIM + dd;
            const float* s1 = s0 + DDIM;
            float4 a0 = *(const float4*)s0, a1 = *(const float4*)(s0 + 4);
            float4 b0 = *(const float4*)s1, b1 = *(const float4*)(s1 + 4);
            float xa[8] = {a0.x, a0.y, a0.z, a0.w, a1.x, a1.y, a1.z, a1.w};
            float xb[8] = {b0.x, b0.y, b0.z, b0.w, b1.x, b1.y, b1.z, b1.w};
#pragma unroll
            for (int j = 0; j < 8; ++j)
                T32[ht_][(dc + j) * 33 + rp] = pk16(xa[j], xb[j]);
        }
    }
    __syncthreads();

    const int dl = t >> 2;          // 0..63
    const int q  = t & 3;
#pragma unroll
    for (int ht_ = 0; ht_ < 2; ++ht_) {
        int d = d0 + (ht_ << 6) + dl;
        if (d < DDIM) {
            unsigned buf[8];
#pragma unroll
            for (int i = 0; i < 8; ++i)
                buf[i] = T32[ht_][dl * 33 + q * 8 + i];
            unsigned* dst = (unsigned*)(XT + ((size_t)b * DDIM + d) * LSEQ + r0) + q * 8;
            *(uint4*)(dst)     = *(uint4*)&buf[0];
            *(uint4*)(dst + 4) = *(uint4*)&buf[4];
        }
    }
}

// ---------------------------------------------------------------------------
// K1: attn[b][p][h] = sum_d P[b][p][d] * H[b][h][d]   (fp32 out)
// R9 proven config: 256 threads, 128x128 tile, reads fp32 directly, hi/lo
// fp16 split in the LDS-write phase, 48 KB dbuf, chunk-XOR swizzle on
// (row>>1)&3 (0 bank conflicts measured). Do NOT add a 2nd launch_bounds arg
// (R10: VGPR capped at 64 -> full accumulator spill, 709 MB scratch traffic).
// ---------------------------------------------------------------------------
__global__ __launch_bounds__(256) void attn_gemm(
    const float* __restrict__ P, const float* __restrict__ H,
    float* __restrict__ attn)
{
    const int bid = blockIdx.x;
    const int swz = (bid & 7) * 128 + (bid >> 3);   // 1024 blocks, 8 XCDs
    const int b  = swz >> 4;
    const int pt = ((swz >> 2) & 3) << 7;
    const int ht = (swz & 3) << 7;
    const float* Pb = P + ((size_t)b * LSEQ + pt) * DDIM;
    const float* Hb = H + ((size_t)b * LSEQ + ht) * DDIM;
    float* Ab = attn + (size_t)b * LSEQ * LSEQ;

    __shared__ _Float16 Ah[2][128 * 32], Al[2][128 * 32], Bh[2][128 * 32];

    const int t    = threadIdx.x;
    const int lane = t & 63;
    const int wave = t >> 6;
    const int wm = (wave >> 1) << 6;
    const int wn = (wave & 1) << 6;
    const int fr = lane & 15;
    const int fq = lane >> 4;
    const int srow = t >> 2;          // 0..63 (r=1 adds 64)
    const int sc8  = (t & 3) << 3;    // logical col chunk base (8 elems)

    const int wchunk = (t & 3) ^ ((srow >> 1) & 3);
    const int woff   = srow * 32 + (wchunk << 3);          // + r*64*32
    const int rcoff  = ((fq ^ ((fr >> 1) & 3)) << 3);

    float4 pf[8];
    const float4 fz = {0.f, 0.f, 0.f, 0.f};
    auto issue = [&](int k0) {
        bool ok = (k0 + sc8) < DDIM;   // zero the 600..607 tail chunk
#pragma unroll
        for (int r = 0; r < 2; ++r) {
            size_t base = (size_t)(srow + (r << 6)) * DDIM + k0 + sc8;
            if (ok) {
                pf[r * 4 + 0] = *(const float4*)(Pb + base);
                pf[r * 4 + 1] = *(const float4*)(Pb + base + 4);
                pf[r * 4 + 2] = *(const float4*)(Hb + base);
                pf[r * 4 + 3] = *(const float4*)(Hb + base + 4);
            } else {
                pf[r * 4 + 0] = fz; pf[r * 4 + 1] = fz;
                pf[r * 4 + 2] = fz; pf[r * 4 + 3] = fz;
            }
        }
    };
    auto wr = [&](int buf) {
#pragma unroll
        for (int r = 0; r < 2; ++r) {
            float4 a0 = pf[r * 4 + 0], a1 = pf[r * 4 + 1];
            float4 h0 = pf[r * 4 + 2], h1 = pf[r * 4 + 3];
            float af[8] = {a0.x, a0.y, a0.z, a0.w, a1.x, a1.y, a1.z, a1.w};
            float hf[8] = {h0.x, h0.y, h0.z, h0.w, h1.x, h1.y, h1.z, h1.w};
            f16x8 hi, lo, bh;
#pragma unroll
            for (int j = 0; j < 8; ++j) {
                hi[j] = (_Float16)af[j];
                lo[j] = (_Float16)(af[j] - (float)hi[j]);
                bh[j] = (_Float16)hf[j];
            }
            int off = woff + (r << 11);                    // r*64*32
            *(f16x8*)&Ah[buf][off] = hi;
            *(f16x8*)&Al[buf][off] = lo;
            *(f16x8*)&Bh[buf][off] = bh;
        }
    };

    issue(0);
    wr(0);
    issue(32);
    __syncthreads();

    f32x4 acc[4][4];
#pragma unroll
    for (int i = 0; i < 4; ++i)
#pragma unroll
        for (int j = 0; j < 4; ++j) acc[i][j] = (f32x4){0.f, 0.f, 0.f, 0.f};

    constexpr int NK = 19;   // ceil(600/32)
    int cur = 0;
    for (int it = 0; it < NK; ++it) {
        f16x8 ah[4], al[4], bh[4];
#pragma unroll
        for (int i = 0; i < 4; ++i) {
            int ra = (wm + (i << 4) + fr) * 32 + rcoff;
            int rb = (wn + (i << 4) + fr) * 32 + rcoff;
            ah[i] = *(const f16x8*)&Ah[cur][ra];
            al[i] = *(const f16x8*)&Al[cur][ra];
            bh[i] = *(const f16x8*)&Bh[cur][rb];
        }
        if (it + 1 < NK) {
            wr(cur ^ 1);                       // cvt + stage tile it+1
            if (it + 2 < NK) issue((it + 2) << 5);
        }
#pragma unroll
        for (int mi = 0; mi < 4; ++mi)
#pragma unroll
            for (int ni = 0; ni < 4; ++ni) {
                f32x4 c = acc[mi][ni];
                c = mfma16h(ah[mi], bh[ni], c);
                c = mfma16h(al[mi], bh[ni], c);
                acc[mi][ni] = c;
            }
        __syncthreads();
        cur ^= 1;
    }

#pragma unroll
    for (int mi = 0; mi < 4; ++mi)
#pragma unroll
        for (int ni = 0; ni < 4; ++ni)
#pragma unroll
            for (int j = 0; j < 4; ++j) {
                int p = pt + wm + (mi << 4) + (fq << 2) + j;
                int h = ht + wn + (ni << 4) + fr;
                Ab[(size_t)p * LSEQ + h] = acc[mi][ni][j];
            }
}

// ---------------------------------------------------------------------------
// K2: stats_w1 — ONE pass over attn per 64-row stripe:
//   per-row (over h): M1, R1, W1 fp16 (hm-masked softmax)
//   per-col partials (over p, pm-masked online): Mp/Tp/Sp [b][8][512]
// ---------------------------------------------------------------------------
__global__ __launch_bounds__(256) void stats_w1(
    const float* __restrict__ attn, const float* __restrict__ hmask,
    const float* __restrict__ pmask,
    float* __restrict__ M1, float* __restrict__ R1,
    _Float16* __restrict__ W1,
    float* __restrict__ Mp, float* __restrict__ Tp, float* __restrict__ Sp)
{
    int b      = blockIdx.x >> 3;
    int stripe = blockIdx.x & 7;
    int lane   = threadIdx.x & 63;
    int wave   = threadIdx.x >> 6;
    const float* hm = hmask + (b << 9);
    const float* pm = pmask + (b << 9);

    float4 m0 = *(const float4*)(hm + (lane << 3));
    float4 m1 = *(const float4*)(hm + (lane << 3) + 4);
    float mk[8] = {m0.x, m0.y, m0.z, m0.w, m1.x, m1.y, m1.z, m1.w};

    float cM[8], cT[8], cS[8];
#pragma unroll
    for (int j = 0; j < 8; ++j) { cM[j] = -1e30f; cT[j] = 0.f; cS[j] = 0.f; }

    for (int i = 0; i < 16; ++i) {
        int row   = (stripe << 6) + (wave << 4) + i;
        int rowid = (b << 9) + row;
        const float* rp = attn + (size_t)rowid * LSEQ + (lane << 3);
        float4 s0 = *(const float4*)rp;
        float4 s1 = *(const float4*)(rp + 4);
        float s[8] = {s0.x, s0.y, s0.z, s0.w, s1.x, s1.y, s1.z, s1.w};

        float v[8];
#pragma unroll
        for (int j = 0; j < 8; ++j) v[j] = s[j] * mk[j];
        float mx = -1e30f;
#pragma unroll
        for (int j = 0; j < 8; ++j) mx = fmaxf(mx, v[j]);
#pragma unroll
        for (int off = 32; off; off >>= 1) mx = fmaxf(mx, __shfl_xor(mx, off));

        float e[8], T = 0.f, S = 0.f;
#pragma unroll
        for (int j = 0; j < 8; ++j) { e[j] = __expf(v[j] - mx); T += mk[j] * e[j]; S += e[j]; }
#pragma unroll
        for (int off = 32; off; off >>= 1) { T += __shfl_xor(T, off); S += __shfl_xor(S, off); }
        float R = 1.f / (T + 1e-13f * S);

        if (W1) {
            union { f16x8 v8; _Float16 h[8]; } wv;
#pragma unroll
            for (int j = 0; j < 8; ++j) wv.h[j] = (_Float16)(mk[j] * e[j] * R);
            *(f16x8*)(W1 + (size_t)rowid * LSEQ + (lane << 3)) = wv.v8;
        }
        if (lane == 0) { M1[rowid] = mx; R1[rowid] = R; }

        float pmv = pm[row];
#pragma unroll
        for (int j = 0; j < 8; ++j) {
            float v2 = s[j] * pmv;
            float nm = fmaxf(cM[j], v2);
            float sc = __expf(cM[j] - nm);
            float e2 = __expf(v2 - nm);
            cT[j] = cT[j] * sc + pmv * e2;
            cS[j] = cS[j] * sc + e2;
            cM[j] = nm;
        }
    }

    __shared__ float LM[4][512], LT[4][512], LS[4][512];
#pragma unroll
    for (int j = 0; j < 8; ++j) {
        int c = (lane << 3) + j;
        LM[wave][c] = cM[j]; LT[wave][c] = cT[j]; LS[wave][c] = cS[j];
    }
    __syncthreads();

    size_t base = (size_t)((b << 3) + stripe) * 512;
    for (int cc = threadIdx.x; cc < 512; cc += 256) {
        float gm = fmaxf(fmaxf(LM[0][cc], LM[1][cc]), fmaxf(LM[2][cc], LM[3][cc]));
        float gT = 0.f, gS = 0.f;
#pragma unroll
        for (int w = 0; w < 4; ++w) {
            float sc = __expf(LM[w][cc] - gm);
            gT += LT[w][cc] * sc;
            gS += LS[w][cc] * sc;
        }
        Mp[base + cc] = gm; Tp[base + cc] = gT; Sp[base + cc] = gS;
    }
}

// ---------------------------------------------------------------------------
// K3 (fallback only): col_merge — merge 8 stripe partials -> M2, R2
// ---------------------------------------------------------------------------
__global__ __launch_bounds__(256) void col_merge(
    const float* __restrict__ Mp, const float* __restrict__ Tp,
    const float* __restrict__ Sp, float* __restrict__ M2, float* __restrict__ R2)
{
    int b = blockIdx.x >> 1;
    int c = ((blockIdx.x & 1) << 8) + threadIdx.x;
    float gm = -1e30f, gT = 0.f, gS = 0.f;
#pragma unroll
    for (int st = 0; st < 8; ++st) {
        size_t idx = (size_t)((b << 3) + st) * 512 + c;
        float m = Mp[idx], tt = Tp[idx], ss = Sp[idx];
        float nm  = fmaxf(gm, m);
        float sc1 = __expf(gm - nm), sc2 = __expf(m - nm);
        gT = gT * sc1 + tt * sc2;
        gS = gS * sc1 + ss * sc2;
        gm = nm;
    }
    M2[(b << 9) + c] = gm;
    R2[(b << 9) + c] = 1.f / (gT + 1e-13f * gS);
}

// ---------------------------------------------------------------------------
// K4: w2gen3 — per-block 8-stripe merge (from Mp/Tp/Sp) then
//   W2[b][h][p] = pm[p] ? exp(attn[b][p][h]-M2[h])*R2[h] : 0 (fp16)
//   u32-paired LDS transpose (2 p-rows per thread). Tile = 64p x 128h.
// ---------------------------------------------------------------------------
__global__ __launch_bounds__(256) void w2gen3(
    const float* __restrict__ attn, const float* __restrict__ pmask,
    const float* __restrict__ Mp, const float* __restrict__ Tp,
    const float* __restrict__ Sp, _Float16* __restrict__ W2)
{
    int blk = blockIdx.x;
    int b  = blk >> 5;
    int p0 = ((blk >> 2) & 7) << 6;
    int h0 = (blk & 3) << 7;
    const float* Ab = attn + (size_t)b * LSEQ * LSEQ;
    const float* pm = pmask + (b << 9);

    __shared__ float sM[128], sR[128];
    __shared__ unsigned T32[128 * 33];
    const int t = threadIdx.x;
    if (t < 128) {
        float gm = -1e30f, gT = 0.f, gS = 0.f;
#pragma unroll
        for (int st = 0; st < 8; ++st) {
            size_t idx = (size_t)((b << 3) + st) * 512 + h0 + t;
            float m = Mp[idx], tt = Tp[idx], ss = Sp[idx];
            float nm  = fmaxf(gm, m);
            float sc1 = __expf(gm - nm), sc2 = __expf(m - nm);
            gT = gT * sc1 + tt * sc2;
            gS = gS * sc1 + ss * sc2;
            gm = nm;
        }
        sM[t] = gm;
        sR[t] = 1.f / (gT + 1e-13f * gS);
    }
    __syncthreads();

#pragma unroll
    for (int it = 0; it < 4; ++it) {
        int g  = t + (it << 8);
        int pp = g >> 5;           // 0..31 p-pair
        int hc = (g & 31) << 2;    // 0..124
        const float* s0 = Ab + (size_t)(p0 + 2 * pp) * LSEQ + h0 + hc;
        float4 xa = *(const float4*)s0;
        float4 xb = *(const float4*)(s0 + LSEQ);
        float pa = pm[p0 + 2 * pp];
        float pb = pm[p0 + 2 * pp + 1];
        float a[4] = {xa.x, xa.y, xa.z, xa.w};
        float bb[4] = {xb.x, xb.y, xb.z, xb.w};
#pragma unroll
        for (int j = 0; j < 4; ++j) {
            float wa = (pa != 0.f) ? __expf(a[j]  - sM[hc + j]) * sR[hc + j] : 0.f;
            float wb = (pb != 0.f) ? __expf(bb[j] - sM[hc + j]) * sR[hc + j] : 0.f;
            T32[(hc + j) * 33 + pp] = pk16(wa, wb);
        }
    }
    __syncthreads();

    const int hl = t >> 1;          // 0..127
    const int q  = t & 1;
    unsigned buf[16];
#pragma unroll
    for (int i = 0; i < 16; ++i)
        buf[i] = T32[hl * 33 + q * 16 + i];
    unsigned* dst = (unsigned*)(W2 + ((size_t)(b << 9) + h0 + hl) * LSEQ + p0) + q * 16;
#pragma unroll
    for (int i = 0; i < 4; ++i)
        *(uint4*)(dst + 4 * i) = *(uint4*)&buf[4 * i];
}

// ---------------------------------------------------------------------------
// K5: out[b][m][d] = mask_m[m] * sum_k W[b][m][k] * BT[b][d][k]   (fp16 MFMA)
//     LDS [128][32] chunk-XOR swizzle keyed on (row>>1)&3 -> 32 KB.
// ---------------------------------------------------------------------------
__global__ __launch_bounds__(256) void gemm_fp16(
    const _Float16* __restrict__ W, const _Float16* __restrict__ BT,
    const float* __restrict__ mask_m, float* __restrict__ out)
{
    const int bid = blockIdx.x;
    const int swz = (bid & 7) * 160 + (bid >> 3);   // 1280 blocks, 8 XCDs
    const int b   = swz / 20;
    const int rem = swz % 20;
    const int m0  = (rem / 5) << 7;
    const int n0  = (rem % 5) << 7;
    const _Float16* Wb = W  + (size_t)b * LSEQ * LSEQ;
    const _Float16* Bb = BT + (size_t)b * DDIM * LSEQ;

    __shared__ _Float16 Wl[2][128 * 32];
    __shared__ _Float16 Bl[2][128 * 32];

    const int t    = threadIdx.x;
    const int lane = t & 63;
    const int wave = t >> 6;
    const int wm = (wave >> 1) << 6;
    const int wn = (wave & 1) << 6;
    const int fr = lane & 15;
    const int fq = lane >> 4;
    const int srow = t >> 2;
    const int sc8  = (t & 3) << 3;

    const int wchunk = (t & 3) ^ ((srow >> 1) & 3);
    const int woff   = srow * 32 + (wchunk << 3);
    const int rcoff  = ((fq ^ ((fr >> 1) & 3)) << 3);

    f16x8 pw[2], pb[2];
    const f16x8 zz = {0, 0, 0, 0, 0, 0, 0, 0};
    auto issue = [&](int k0) {
#pragma unroll
        for (int r = 0; r < 2; ++r) {
            int row = srow + (r << 6);
            pw[r] = *(const f16x8*)(Wb + (size_t)(m0 + row) * LSEQ + k0 + sc8);
            int nrow = n0 + row;
            pb[r] = (nrow < DDIM) ? *(const f16x8*)(Bb + (size_t)nrow * LSEQ + k0 + sc8) : zz;
        }
    };
    auto wr = [&](int buf) {
#pragma unroll
        for (int r = 0; r < 2; ++r) {
            int off = woff + (r << 11);
            *(f16x8*)&Wl[buf][off] = pw[r];
            *(f16x8*)&Bl[buf][off] = pb[r];
        }
    };

    issue(0);
    wr(0);
    issue(32);
    __syncthreads();

    f32x4 acc[4][4];
#pragma unroll
    for (int i = 0; i < 4; ++i)
#pragma unroll
        for (int j = 0; j < 4; ++j) acc[i][j] = (f32x4){0.f, 0.f, 0.f, 0.f};

    constexpr int NK = 16;   // 512/32
    int cur = 0;
    for (int it = 0; it < NK; ++it) {
        f16x8 af[4], bfr[4];
#pragma unroll
        for (int i = 0; i < 4; ++i) {
            af[i]  = *(const f16x8*)&Wl[cur][(wm + (i << 4) + fr) * 32 + rcoff];
            bfr[i] = *(const f16x8*)&Bl[cur][(wn + (i << 4) + fr) * 32 + rcoff];
        }
        if (it + 1 < NK) {
            wr(cur ^ 1);
            if (it + 2 < NK) issue((it + 2) << 5);
        }
#pragma unroll
        for (int mi = 0; mi < 4; ++mi)
#pragma unroll
            for (int ni = 0; ni < 4; ++ni)
                acc[mi][ni] = mfma16h(af[mi], bfr[ni], acc[mi][ni]);
        __syncthreads();
        cur ^= 1;
    }

    const float* mmb = mask_m + (b << 9) + m0;
#pragma unroll
    for (int mi = 0; mi < 4; ++mi)
#pragma unroll
        for (int j = 0; j < 4; ++j) {
            int row = wm + (mi << 4) + (fq << 2) + j;
            float mm = mmb[row];
#pragma unroll
            for (int ni = 0; ni < 4; ++ni) {
                int d = n0 + wn + (ni << 4) + fr;
                if (d < DDIM)
                    out[((size_t)(b << 9) + m0 + row) * DDIM + d] = mm * acc[mi][ni][j];
            }
        }
}

// ---------------------------------------------------------------------------
// Fallback wsum (round-1 style) — only if ws_size too small for fast path
// ---------------------------------------------------------------------------
template <int TRANSA>
__global__ __launch_bounds__(256) void wsum(
    const float* __restrict__ attn, const float* __restrict__ Bsrc,
    const float* __restrict__ mask_k, const float* __restrict__ mask_m,
    const float* __restrict__ Mst, const float* __restrict__ Rst,
    float* __restrict__ out)
{
    const int blk = blockIdx.x;
    const int b   = blk / 20;
    const int rem = blk % 20;
    const int m0  = (rem / 5) << 7;
    const int n0  = (rem % 5) << 7;

    const float* Ab  = attn + (size_t)b * LSEQ * LSEQ;
    const float* Bb  = Bsrc + (size_t)b * LSEQ * DDIM;
    const float* mkb = mask_k + (b << 9);

    __shared__ unsigned short Wl[128 * LDP];
    __shared__ unsigned short Bl[128 * LDP];
    __shared__ float Ml[128], Rl[128], Mm[128];

    const int t    = threadIdx.x;
    const int lane = t & 63;
    const int wave = t >> 6;
    const int wm = (wave >> 1) << 6;
    const int wn = (wave & 1) << 6;
    const int fr = lane & 15;
    const int fq = lane >> 4;

    if (t < 128) {
        Ml[t] = Mst[(b << 9) + m0 + t];
        Rl[t] = Rst[(b << 9) + m0 + t];
        Mm[t] = mask_m[(b << 9) + m0 + t];
    }
    __syncthreads();

    f32x4 acc[4][4];
#pragma unroll
    for (int i = 0; i < 4; ++i)
#pragma unroll
        for (int j = 0; j < 4; ++j) acc[i][j] = (f32x4){0.f, 0.f, 0.f, 0.f};

    for (int k0 = 0; k0 < LSEQ; k0 += 32) {
        if constexpr (TRANSA == 0) {
#pragma unroll
            for (int r = 0; r < 4; ++r) {
                int idx = t + (r << 8);
                int row = idx >> 3;
                int c4  = (idx & 7) << 2;
                float4 x  = *(const float4*)(Ab + (size_t)(m0 + row) * LSEQ + k0 + c4);
                float4 km = *(const float4*)(mkb + k0 + c4);
                float Mv = Ml[row], Rv = Rl[row];
                ushort4 w;
                w.x = (km.x != 0.f) ? f2bf(__expf(x.x - Mv) * Rv) : (unsigned short)0;
                w.y = (km.y != 0.f) ? f2bf(__expf(x.y - Mv) * Rv) : (unsigned short)0;
                w.z = (km.z != 0.f) ? f2bf(__expf(x.z - Mv) * Rv) : (unsigned short)0;
                w.w = (km.w != 0.f) ? f2bf(__expf(x.w - Mv) * Rv) : (unsigned short)0;
                *(ushort4*)&Wl[row * LDP + c4] = w;
            }
        } else {
#pragma unroll
            for (int r = 0; r < 4; ++r) {
                int mh = t & 127;
                int pq = (t >> 7) + (r << 1);
                float Mv = Ml[mh], Rv = Rl[mh];
                ushort4 w;
#pragma unroll
                for (int j = 0; j < 4; ++j) {
                    int k = k0 + (pq << 2) + j;
                    float x  = Ab[(size_t)k * LSEQ + m0 + mh];
                    float km = mkb[k];
                    ((unsigned short*)&w)[j] =
                        (km != 0.f) ? f2bf(__expf(x - Mv) * Rv) : (unsigned short)0;
                }
                *(ushort4*)&Wl[mh * LDP + (pq << 2)] = w;
            }
        }
#pragma unroll
        for (int r = 0; r < 4; ++r) {
            int d  = t & 127;
            int kq = (t >> 7) + (r << 1);
            bool valid = (n0 + d) < DDIM;
            ushort4 v;
#pragma unroll
            for (int j = 0; j < 4; ++j) {
                int k = k0 + (kq << 2) + j;
                float x = valid ? Bb[(size_t)k * DDIM + n0 + d] : 0.f;
                ((unsigned short*)&v)[j] = f2bf(x);
            }
            *(ushort4*)&Bl[d * LDP + (kq << 2)] = v;
        }
        __syncthreads();

        short8 af[4], bfr[4];
#pragma unroll
        for (int i = 0; i < 4; ++i) {
            af[i]  = *(const short8*)&Wl[(wm + (i << 4) + fr) * LDP + (fq << 3)];
            bfr[i] = *(const short8*)&Bl[(wn + (i << 4) + fr) * LDP + (fq << 3)];
        }
#pragma unroll
        for (int mi = 0; mi < 4; ++mi)
#pragma unroll
            for (int ni = 0; ni < 4; ++ni)
                acc[mi][ni] = mfma16(af[mi], bfr[ni], acc[mi][ni]);
        __syncthreads();
    }

#pragma unroll
    for (int mi = 0; mi < 4; ++mi)
#pragma unroll
        for (int j = 0; j < 4; ++j) {
            int row = wm + (mi << 4) + (fq << 2) + j;
            float mm = Mm[row];
#pragma unroll
            for (int ni = 0; ni < 4; ++ni) {
                int d = n0 + wn + (ni << 4) + fr;
                if (d < DDIM)
                    out[((size_t)(b << 9) + m0 + row) * DDIM + d] = mm * acc[mi][ni][j];
            }
        }
}

// ---------------------------------------------------------------------------
extern "C" void kernel_launch(void* const* d_in, const int* in_sizes, int n_in,
                              void* d_out, int out_size, void* d_ws, size_t ws_size,
                              hipStream_t stream)
{
    const float* P  = (const float*)d_in[0];   // encoded_premise   [64,512,600]
    const float* pm = (const float*)d_in[1];   // premise_mask      [64,512]
    const float* H  = (const float*)d_in[2];   // encoded_hypothesis[64,512,600]
    const float* hm = (const float*)d_in[3];   // hypothesis_mask   [64,512]
    float* out = (float*)d_out;
    char* o  = (char*)d_out;
    char* ws = (char*)d_ws;

    const size_t E = (size_t)DEVB * LSEQ * DDIM;   // 19,660,800 out-elems per half

    // d_out scratch layout (upper half only; dead before gemms write):
    //   hT [78,643,200 : 117,964,800) fp16 | W1 [117,964,800 : 151,519,232) fp16
    _Float16* hT = (_Float16*)(o + 78643200);
    _Float16* W1 = (_Float16*)(o + 117964800);

    // ws layout (fast path):
    //   attn fp32 [0 : 67.11M) | pT [67.11 : 106.43M) | W2 [106.43 : 139.98M)
    //   Mp/Tp/Sp [139.98 : 143.13M) | M1/R1 [143.13 : 143.65M)
    const size_t fast_need = 143654912;

    if (ws_size >= fast_need) {
        float*     attn = (float*)ws;
        _Float16*  pT   = (_Float16*)(ws + 67108864);
        _Float16*  W2   = (_Float16*)(ws + 67108864 + 39321600);
        float*     Mp   = (float*)(ws + 139984896);
        float*     Tp   = Mp + (size_t)DEVB * 8 * 512;
        float*     Sp   = Tp + (size_t)DEVB * 8 * 512;
        float*     M1   = Sp + (size_t)DEVB * 8 * 512;
        float*     R1   = M1 + DEVB * LSEQ;

        transcvt3<<<DEVB * 80, 256, 0, stream>>>(P, H, pT, hT);
        attn_gemm<<<DEVB * 16, 256, 0, stream>>>(P, H, attn);
        stats_w1<<<DEVB * 8, 256, 0, stream>>>(attn, hm, pm, M1, R1, W1, Mp, Tp, Sp);
        w2gen3<<<DEVB * 32, 256, 0, stream>>>(attn, pm, Mp, Tp, Sp, W2);
        gemm_fp16<<<DEVB * 20, 256, 0, stream>>>(W1, hT, pm, out);
        gemm_fp16<<<DEVB * 20, 256, 0, stream>>>(W2, pT, hm, out + E);
    } else {
        // fallback: attn + partials + stats = 70.78 MB of ws; no prep needed
        float* attn = (float*)ws;
        float* Mp   = (float*)(ws + 67108864);
        float* Tp   = Mp + (size_t)DEVB * 8 * 512;
        float* Sp   = Tp + (size_t)DEVB * 8 * 512;
        float* M1   = Sp + (size_t)DEVB * 8 * 512;
        float* R1   = M1 + DEVB * LSEQ;
        float* M2   = R1 + DEVB * LSEQ;
        float* R2   = M2 + DEVB * LSEQ;

        attn_gemm<<<DEVB * 16, 256, 0, stream>>>(P, H, attn);
        stats_w1<<<DEVB * 8, 256, 0, stream>>>(attn, hm, pm, M1, R1, nullptr, Mp, Tp, Sp);
        col_merge<<<DEVB * 2, 256, 0, stream>>>(Mp, Tp, Sp, M2, R2);
        wsum<0><<<DEVB * 20, 256, 0, stream>>>(attn, H, hm, pm, M1, R1, out);
        wsum<1><<<DEVB * 20, 256, 0, stream>>>(attn, P, pm, hm, M2, R2, out + E);
    }
}

// Round 13
// 315.149 us; speedup vs baseline: 1.6620x; 1.0198x over previous
//
#include <hip/hip_runtime.h>
#include <hip/hip_bf16.h>

#define DEVB 64
#define LSEQ 512
#define DDIM 600

typedef short short8 __attribute__((ext_vector_type(8)));
typedef float f32x4 __attribute__((ext_vector_type(4)));
typedef _Float16 f16x8 __attribute__((ext_vector_type(8)));
typedef _Float16 f16x4 __attribute__((ext_vector_type(4)));

constexpr int LDP = 40;   // padded stride for fallback-wsum tiles (16B-aligned rows)

__device__ __forceinline__ unsigned short f2bf(float x) {
    union { float f; unsigned u; } v; v.f = x;
    unsigned r = v.u + 0x7fffu + ((v.u >> 16) & 1u);   // RNE
    return (unsigned short)(r >> 16);
}
__device__ __forceinline__ unsigned pk16(float a, float b) {
    union { _Float16 h[2]; unsigned u; } p;
    p.h[0] = (_Float16)a; p.h[1] = (_Float16)b;
    return p.u;
}
__device__ __forceinline__ f32x4 mfma16(short8 a, short8 b, f32x4 c) {
    return __builtin_amdgcn_mfma_f32_16x16x32_bf16(a, b, c, 0, 0, 0);
}
__device__ __forceinline__ f32x4 mfma16h(f16x8 a, f16x8 b, f32x4 c) {
    return __builtin_amdgcn_mfma_f32_16x16x32_f16(a, b, c, 0, 0, 0);
}

// ---------------------------------------------------------------------------
// K1: attn[b][p][h] = sum_d P[b][p][d] * H[b][h][d]   (fp32 out)
// R9 proven config: 256 threads, 128x128 tile, reads fp32 directly, hi/lo
// fp16 split in the LDS-write phase, 48 KB dbuf, chunk-XOR swizzle on
// (row>>1)&3 (0 bank conflicts measured). Do NOT add a 2nd launch_bounds arg
// (R10: VGPR capped at 64 -> full accumulator spill, 709 MB scratch traffic).
// ---------------------------------------------------------------------------
__global__ __launch_bounds__(256) void attn_gemm(
    const float* __restrict__ P, const float* __restrict__ H,
    float* __restrict__ attn)
{
    const int bid = blockIdx.x;
    const int swz = (bid & 7) * 128 + (bid >> 3);   // 1024 blocks, 8 XCDs
    const int b  = swz >> 4;
    const int pt = ((swz >> 2) & 3) << 7;
    const int ht = (swz & 3) << 7;
    const float* Pb = P + ((size_t)b * LSEQ + pt) * DDIM;
    const float* Hb = H + ((size_t)b * LSEQ + ht) * DDIM;
    float* Ab = attn + (size_t)b * LSEQ * LSEQ;

    __shared__ _Float16 Ah[2][128 * 32], Al[2][128 * 32], Bh[2][128 * 32];

    const int t    = threadIdx.x;
    const int lane = t & 63;
    const int wave = t >> 6;
    const int wm = (wave >> 1) << 6;
    const int wn = (wave & 1) << 6;
    const int fr = lane & 15;
    const int fq = lane >> 4;
    const int srow = t >> 2;          // 0..63 (r=1 adds 64)
    const int sc8  = (t & 3) << 3;    // logical col chunk base (8 elems)

    const int wchunk = (t & 3) ^ ((srow >> 1) & 3);
    const int woff   = srow * 32 + (wchunk << 3);          // + r*64*32
    const int rcoff  = ((fq ^ ((fr >> 1) & 3)) << 3);

    float4 pf[8];
    const float4 fz = {0.f, 0.f, 0.f, 0.f};
    auto issue = [&](int k0) {
        bool ok = (k0 + sc8) < DDIM;   // zero the 600..607 tail chunk
#pragma unroll
        for (int r = 0; r < 2; ++r) {
            size_t base = (size_t)(srow + (r << 6)) * DDIM + k0 + sc8;
            if (ok) {
                pf[r * 4 + 0] = *(const float4*)(Pb + base);
                pf[r * 4 + 1] = *(const float4*)(Pb + base + 4);
                pf[r * 4 + 2] = *(const float4*)(Hb + base);
                pf[r * 4 + 3] = *(const float4*)(Hb + base + 4);
            } else {
                pf[r * 4 + 0] = fz; pf[r * 4 + 1] = fz;
                pf[r * 4 + 2] = fz; pf[r * 4 + 3] = fz;
            }
        }
    };
    auto wr = [&](int buf) {
#pragma unroll
        for (int r = 0; r < 2; ++r) {
            float4 a0 = pf[r * 4 + 0], a1 = pf[r * 4 + 1];
            float4 h0 = pf[r * 4 + 2], h1 = pf[r * 4 + 3];
            float af[8] = {a0.x, a0.y, a0.z, a0.w, a1.x, a1.y, a1.z, a1.w};
            float hf[8] = {h0.x, h0.y, h0.z, h0.w, h1.x, h1.y, h1.z, h1.w};
            f16x8 hi, lo, bh;
#pragma unroll
            for (int j = 0; j < 8; ++j) {
                hi[j] = (_Float16)af[j];
                lo[j] = (_Float16)(af[j] - (float)hi[j]);
                bh[j] = (_Float16)hf[j];
            }
            int off = woff + (r << 11);                    // r*64*32
            *(f16x8*)&Ah[buf][off] = hi;
            *(f16x8*)&Al[buf][off] = lo;
            *(f16x8*)&Bh[buf][off] = bh;
        }
    };

    issue(0);
    wr(0);
    issue(32);
    __syncthreads();

    f32x4 acc[4][4];
#pragma unroll
    for (int i = 0; i < 4; ++i)
#pragma unroll
        for (int j = 0; j < 4; ++j) acc[i][j] = (f32x4){0.f, 0.f, 0.f, 0.f};

    constexpr int NK = 19;   // ceil(600/32)
    int cur = 0;
    for (int it = 0; it < NK; ++it) {
        f16x8 ah[4], al[4], bh[4];
#pragma unroll
        for (int i = 0; i < 4; ++i) {
            int ra = (wm + (i << 4) + fr) * 32 + rcoff;
            int rb = (wn + (i << 4) + fr) * 32 + rcoff;
            ah[i] = *(const f16x8*)&Ah[cur][ra];
            al[i] = *(const f16x8*)&Al[cur][ra];
            bh[i] = *(const f16x8*)&Bh[cur][rb];
        }
        if (it + 1 < NK) {
            wr(cur ^ 1);                       // cvt + stage tile it+1
            if (it + 2 < NK) issue((it + 2) << 5);
        }
#pragma unroll
        for (int mi = 0; mi < 4; ++mi)
#pragma unroll
            for (int ni = 0; ni < 4; ++ni) {
                f32x4 c = acc[mi][ni];
                c = mfma16h(ah[mi], bh[ni], c);
                c = mfma16h(al[mi], bh[ni], c);
                acc[mi][ni] = c;
            }
        __syncthreads();
        cur ^= 1;
    }

#pragma unroll
    for (int mi = 0; mi < 4; ++mi)
#pragma unroll
        for (int ni = 0; ni < 4; ++ni)
#pragma unroll
            for (int j = 0; j < 4; ++j) {
                int p = pt + wm + (mi << 4) + (fq << 2) + j;
                int h = ht + wn + (ni << 4) + fr;
                Ab[(size_t)p * LSEQ + h] = acc[mi][ni][j];
            }
}

// ---------------------------------------------------------------------------
// K2: stats_w1 — ONE pass over attn per 64-row stripe:
//   per-row (over h): M1, R1, W1 fp16 (hm-masked softmax)
//   per-col partials (over p, pm-masked online): Mp/Tp/Sp [b][8][512]
// ---------------------------------------------------------------------------
__global__ __launch_bounds__(256) void stats_w1(
    const float* __restrict__ attn, const float* __restrict__ hmask,
    const float* __restrict__ pmask,
    float* __restrict__ M1, float* __restrict__ R1,
    _Float16* __restrict__ W1,
    float* __restrict__ Mp, float* __restrict__ Tp, float* __restrict__ Sp)
{
    int b      = blockIdx.x >> 3;
    int stripe = blockIdx.x & 7;
    int lane   = threadIdx.x & 63;
    int wave   = threadIdx.x >> 6;
    const float* hm = hmask + (b << 9);
    const float* pm = pmask + (b << 9);

    float4 m0 = *(const float4*)(hm + (lane << 3));
    float4 m1 = *(const float4*)(hm + (lane << 3) + 4);
    float mk[8] = {m0.x, m0.y, m0.z, m0.w, m1.x, m1.y, m1.z, m1.w};

    float cM[8], cT[8], cS[8];
#pragma unroll
    for (int j = 0; j < 8; ++j) { cM[j] = -1e30f; cT[j] = 0.f; cS[j] = 0.f; }

    for (int i = 0; i < 16; ++i) {
        int row   = (stripe << 6) + (wave << 4) + i;
        int rowid = (b << 9) + row;
        const float* rp = attn + (size_t)rowid * LSEQ + (lane << 3);
        float4 s0 = *(const float4*)rp;
        float4 s1 = *(const float4*)(rp + 4);
        float s[8] = {s0.x, s0.y, s0.z, s0.w, s1.x, s1.y, s1.z, s1.w};

        float v[8];
#pragma unroll
        for (int j = 0; j < 8; ++j) v[j] = s[j] * mk[j];
        float mx = -1e30f;
#pragma unroll
        for (int j = 0; j < 8; ++j) mx = fmaxf(mx, v[j]);
#pragma unroll
        for (int off = 32; off; off >>= 1) mx = fmaxf(mx, __shfl_xor(mx, off));

        float e[8], T = 0.f, S = 0.f;
#pragma unroll
        for (int j = 0; j < 8; ++j) { e[j] = __expf(v[j] - mx); T += mk[j] * e[j]; S += e[j]; }
#pragma unroll
        for (int off = 32; off; off >>= 1) { T += __shfl_xor(T, off); S += __shfl_xor(S, off); }
        float R = 1.f / (T + 1e-13f * S);

        if (W1) {
            union { f16x8 v8; _Float16 h[8]; } wv;
#pragma unroll
            for (int j = 0; j < 8; ++j) wv.h[j] = (_Float16)(mk[j] * e[j] * R);
            *(f16x8*)(W1 + (size_t)rowid * LSEQ + (lane << 3)) = wv.v8;
        }
        if (lane == 0) { M1[rowid] = mx; R1[rowid] = R; }

        float pmv = pm[row];
#pragma unroll
        for (int j = 0; j < 8; ++j) {
            float v2 = s[j] * pmv;
            float nm = fmaxf(cM[j], v2);
            float sc = __expf(cM[j] - nm);
            float e2 = __expf(v2 - nm);
            cT[j] = cT[j] * sc + pmv * e2;
            cS[j] = cS[j] * sc + e2;
            cM[j] = nm;
        }
    }

    __shared__ float LM[4][512], LT[4][512], LS[4][512];
#pragma unroll
    for (int j = 0; j < 8; ++j) {
        int c = (lane << 3) + j;
        LM[wave][c] = cM[j]; LT[wave][c] = cT[j]; LS[wave][c] = cS[j];
    }
    __syncthreads();

    size_t base = (size_t)((b << 3) + stripe) * 512;
    for (int cc = threadIdx.x; cc < 512; cc += 256) {
        float gm = fmaxf(fmaxf(LM[0][cc], LM[1][cc]), fmaxf(LM[2][cc], LM[3][cc]));
        float gT = 0.f, gS = 0.f;
#pragma unroll
        for (int w = 0; w < 4; ++w) {
            float sc = __expf(LM[w][cc] - gm);
            gT += LT[w][cc] * sc;
            gS += LS[w][cc] * sc;
        }
        Mp[base + cc] = gm; Tp[base + cc] = gT; Sp[base + cc] = gS;
    }
}

// ---------------------------------------------------------------------------
// K3 (fallback only): col_merge — merge 8 stripe partials -> M2, R2
// ---------------------------------------------------------------------------
__global__ __launch_bounds__(256) void col_merge(
    const float* __restrict__ Mp, const float* __restrict__ Tp,
    const float* __restrict__ Sp, float* __restrict__ M2, float* __restrict__ R2)
{
    int b = blockIdx.x >> 1;
    int c = ((blockIdx.x & 1) << 8) + threadIdx.x;
    float gm = -1e30f, gT = 0.f, gS = 0.f;
#pragma unroll
    for (int st = 0; st < 8; ++st) {
        size_t idx = (size_t)((b << 3) + st) * 512 + c;
        float m = Mp[idx], tt = Tp[idx], ss = Sp[idx];
        float nm  = fmaxf(gm, m);
        float sc1 = __expf(gm - nm), sc2 = __expf(m - nm);
        gT = gT * sc1 + tt * sc2;
        gS = gS * sc1 + ss * sc2;
        gm = nm;
    }
    M2[(b << 9) + c] = gm;
    R2[(b << 9) + c] = 1.f / (gT + 1e-13f * gS);
}

// ---------------------------------------------------------------------------
// K4: w2gen3 — per-block 8-stripe merge (from Mp/Tp/Sp) then
//   W2[b][h][p] = pm[p] ? exp(attn[b][p][h]-M2[h])*R2[h] : 0 (fp16)
//   u32-paired LDS transpose (2 p-rows per thread). Tile = 64p x 128h.
// ---------------------------------------------------------------------------
__global__ __launch_bounds__(256) void w2gen3(
    const float* __restrict__ attn, const float* __restrict__ pmask,
    const float* __restrict__ Mp, const float* __restrict__ Tp,
    const float* __restrict__ Sp, _Float16* __restrict__ W2)
{
    int blk = blockIdx.x;
    int b  = blk >> 5;
    int p0 = ((blk >> 2) & 7) << 6;
    int h0 = (blk & 3) << 7;
    const float* Ab = attn + (size_t)b * LSEQ * LSEQ;
    const float* pm = pmask + (b << 9);

    __shared__ float sM[128], sR[128];
    __shared__ unsigned T32[128 * 33];
    const int t = threadIdx.x;
    if (t < 128) {
        float gm = -1e30f, gT = 0.f, gS = 0.f;
#pragma unroll
        for (int st = 0; st < 8; ++st) {
            size_t idx = (size_t)((b << 3) + st) * 512 + h0 + t;
            float m = Mp[idx], tt = Tp[idx], ss = Sp[idx];
            float nm  = fmaxf(gm, m);
            float sc1 = __expf(gm - nm), sc2 = __expf(m - nm);
            gT = gT * sc1 + tt * sc2;
            gS = gS * sc1 + ss * sc2;
            gm = nm;
        }
        sM[t] = gm;
        sR[t] = 1.f / (gT + 1e-13f * gS);
    }
    __syncthreads();

#pragma unroll
    for (int it = 0; it < 4; ++it) {
        int g  = t + (it << 8);
        int pp = g >> 5;           // 0..31 p-pair
        int hc = (g & 31) << 2;    // 0..124
        const float* s0 = Ab + (size_t)(p0 + 2 * pp) * LSEQ + h0 + hc;
        float4 xa = *(const float4*)s0;
        float4 xb = *(const float4*)(s0 + LSEQ);
        float pa = pm[p0 + 2 * pp];
        float pb = pm[p0 + 2 * pp + 1];
        float a[4] = {xa.x, xa.y, xa.z, xa.w};
        float bb[4] = {xb.x, xb.y, xb.z, xb.w};
#pragma unroll
        for (int j = 0; j < 4; ++j) {
            float wa = (pa != 0.f) ? __expf(a[j]  - sM[hc + j]) * sR[hc + j] : 0.f;
            float wb = (pb != 0.f) ? __expf(bb[j] - sM[hc + j]) * sR[hc + j] : 0.f;
            T32[(hc + j) * 33 + pp] = pk16(wa, wb);
        }
    }
    __syncthreads();

    const int hl = t >> 1;          // 0..127
    const int q  = t & 1;
    unsigned buf[16];
#pragma unroll
    for (int i = 0; i < 16; ++i)
        buf[i] = T32[hl * 33 + q * 16 + i];
    unsigned* dst = (unsigned*)(W2 + ((size_t)(b << 9) + h0 + hl) * LSEQ + p0) + q * 16;
#pragma unroll
    for (int i = 0; i < 4; ++i)
        *(uint4*)(dst + 4 * i) = *(uint4*)&buf[4 * i];
}

// ---------------------------------------------------------------------------
// K5: gemm_dual — BOTH weighted sums in one dispatch (2560 blocks).
//   half 0: out[b][p][d] = pm[p] * sum_h W1[b][p][h] * fp16(H[b][h][d])
//   half 1: out2[b][h][d] = hm[h] * sum_p W2[b][h][p] * fp16(P[b][p][d])
// B operand staged DIRECTLY from row-major fp32 X via u32-pair LDS transpose:
//   Bl[d][kpair] u32, row stride 20 u32 (16B-aligned b128 reads, min-conflict),
//   writes phase-rotated by dg (2-way banks; without rotation it's 16-way).
// A operand (W) staged as before with chunk-XOR swizzle.
// ---------------------------------------------------------------------------
__global__ __launch_bounds__(256) void gemm_dual(
    const _Float16* __restrict__ W1, const _Float16* __restrict__ W2,
    const float* __restrict__ P, const float* __restrict__ H,
    const float* __restrict__ pmask, const float* __restrict__ hmask,
    float* __restrict__ out)
{
    int bid = blockIdx.x;
    const _Float16* W; const float* Bsrc; const float* maskm; float* o;
    if (bid < DEVB * 20) {
        W = W1; Bsrc = H; maskm = pmask; o = out;
    } else {
        bid -= DEVB * 20;
        W = W2; Bsrc = P; maskm = hmask;
        o = out + (size_t)DEVB * LSEQ * DDIM;
    }
    const int swz = (bid & 7) * 160 + (bid >> 3);   // 1280 blocks/half, 8 XCDs
    const int b   = swz / 20;
    const int rem = swz % 20;
    const int m0  = (rem / 5) << 7;
    const int n0  = (rem % 5) << 7;
    const _Float16* Wb = W + (size_t)b * LSEQ * LSEQ;
    const float*    Bb = Bsrc + (size_t)b * LSEQ * DDIM;

    __shared__ _Float16 Wl[2][128 * 32];       // 8 KB x2
    __shared__ unsigned Bl[2][128 * 20];       // 10 KB x2  (u32 k-pairs, pad 20)

    const int t    = threadIdx.x;
    const int lane = t & 63;
    const int wave = t >> 6;
    const int wm = (wave >> 1) << 6;
    const int wn = (wave & 1) << 6;
    const int fr = lane & 15;
    const int fq = lane >> 4;

    // A staging (W, fp16 row-major)
    const int srow = t >> 2;                   // 0..63
    const int sc8  = (t & 3) << 3;
    const int wchunk = (t & 3) ^ ((srow >> 1) & 3);
    const int woffA  = srow * 32 + (wchunk << 3);
    const int rcoff  = ((fq ^ ((fr >> 1) & 3)) << 3);

    // B staging (X fp32 -> transposed fp16 pairs): thread = (kp, dg)
    const int kp = t >> 4;                     // 0..15 k-pair
    const int dg = t & 15;                     // 0..15 d-group (8 cols)
    const int dcol = n0 + (dg << 3);
    const bool bok = dcol < DDIM;              // 8-chunks cleanly valid (600%8==0)

    f16x8 pw[2];
    float4 pbv[4];
    const float4 fz = {0.f, 0.f, 0.f, 0.f};
    auto issue = [&](int k0) {
        pw[0] = *(const f16x8*)(Wb + (size_t)(m0 + srow) * LSEQ + k0 + sc8);
        pw[1] = *(const f16x8*)(Wb + (size_t)(m0 + srow + 64) * LSEQ + k0 + sc8);
        if (bok) {
            const float* r0 = Bb + (size_t)(k0 + 2 * kp) * DDIM + dcol;
            const float* r1 = r0 + DDIM;
            pbv[0] = *(const float4*)r0;
            pbv[1] = *(const float4*)(r0 + 4);
            pbv[2] = *(const float4*)r1;
            pbv[3] = *(const float4*)(r1 + 4);
        } else { pbv[0] = fz; pbv[1] = fz; pbv[2] = fz; pbv[3] = fz; }
    };
    auto wr = [&](int buf) {
        *(f16x8*)&Wl[buf][woffA]             = pw[0];
        *(f16x8*)&Wl[buf][woffA + (64 * 32)] = pw[1];
        float a[8] = {pbv[0].x, pbv[0].y, pbv[0].z, pbv[0].w,
                      pbv[1].x, pbv[1].y, pbv[1].z, pbv[1].w};
        float c[8] = {pbv[2].x, pbv[2].y, pbv[2].z, pbv[2].w,
                      pbv[3].x, pbv[3].y, pbv[3].z, pbv[3].w};
        unsigned w[8];
#pragma unroll
        for (int j = 0; j < 8; ++j) w[j] = pk16(a[j], c[j]);
#pragma unroll
        for (int jo = 0; jo < 8; ++jo) {
            int jj = (jo + dg) & 7;            // phase rotation -> 2-way banks
            Bl[buf][((dg << 3) + jj) * 20 + kp] = w[jj];
        }
    };

    issue(0);
    wr(0);
    issue(32);
    __syncthreads();

    f32x4 acc[4][4];
#pragma unroll
    for (int i = 0; i < 4; ++i)
#pragma unroll
        for (int j = 0; j < 4; ++j) acc[i][j] = (f32x4){0.f, 0.f, 0.f, 0.f};

    constexpr int NK = 16;   // 512/32
    int cur = 0;
    for (int it = 0; it < NK; ++it) {
        f16x8 af[4], bfr[4];
#pragma unroll
        for (int i = 0; i < 4; ++i) {
            af[i] = *(const f16x8*)&Wl[cur][(wm + (i << 4) + fr) * 32 + rcoff];
            union { uint4 u; f16x8 h; } bu;
            bu.u = *(const uint4*)&Bl[cur][(wn + (i << 4) + fr) * 20 + (fq << 2)];
            bfr[i] = bu.h;
        }
        if (it + 1 < NK) {
            wr(cur ^ 1);
            if (it + 2 < NK) issue((it + 2) << 5);
        }
#pragma unroll
        for (int mi = 0; mi < 4; ++mi)
#pragma unroll
            for (int ni = 0; ni < 4; ++ni)
                acc[mi][ni] = mfma16h(af[mi], bfr[ni], acc[mi][ni]);
        __syncthreads();
        cur ^= 1;
    }

    const float* mmb = maskm + (b << 9) + m0;
#pragma unroll
    for (int mi = 0; mi < 4; ++mi)
#pragma unroll
        for (int j = 0; j < 4; ++j) {
            int row = wm + (mi << 4) + (fq << 2) + j;
            float mm = mmb[row];
#pragma unroll
            for (int ni = 0; ni < 4; ++ni) {
                int d = n0 + wn + (ni << 4) + fr;
                if (d < DDIM)
                    o[((size_t)(b << 9) + m0 + row) * DDIM + d] = mm * acc[mi][ni][j];
            }
        }
}

// ---------------------------------------------------------------------------
// Fallback wsum (round-1 style) — only if ws_size too small for fast path
// ---------------------------------------------------------------------------
template <int TRANSA>
__global__ __launch_bounds__(256) void wsum(
    const float* __restrict__ attn, const float* __restrict__ Bsrc,
    const float* __restrict__ mask_k, const float* __restrict__ mask_m,
    const float* __restrict__ Mst, const float* __restrict__ Rst,
    float* __restrict__ out)
{
    const int blk = blockIdx.x;
    const int b   = blk / 20;
    const int rem = blk % 20;
    const int m0  = (rem / 5) << 7;
    const int n0  = (rem % 5) << 7;

    const float* Ab  = attn + (size_t)b * LSEQ * LSEQ;
    const float* Bb  = Bsrc + (size_t)b * LSEQ * DDIM;
    const float* mkb = mask_k + (b << 9);

    __shared__ unsigned short Wl[128 * LDP];
    __shared__ unsigned short Bl[128 * LDP];
    __shared__ float Ml[128], Rl[128], Mm[128];

    const int t    = threadIdx.x;
    const int lane = t & 63;
    const int wave = t >> 6;
    const int wm = (wave >> 1) << 6;
    const int wn = (wave & 1) << 6;
    const int fr = lane & 15;
    const int fq = lane >> 4;

    if (t < 128) {
        Ml[t] = Mst[(b << 9) + m0 + t];
        Rl[t] = Rst[(b << 9) + m0 + t];
        Mm[t] = mask_m[(b << 9) + m0 + t];
    }
    __syncthreads();

    f32x4 acc[4][4];
#pragma unroll
    for (int i = 0; i < 4; ++i)
#pragma unroll
        for (int j = 0; j < 4; ++j) acc[i][j] = (f32x4){0.f, 0.f, 0.f, 0.f};

    for (int k0 = 0; k0 < LSEQ; k0 += 32) {
        if constexpr (TRANSA == 0) {
#pragma unroll
            for (int r = 0; r < 4; ++r) {
                int idx = t + (r << 8);
                int row = idx >> 3;
                int c4  = (idx & 7) << 2;
                float4 x  = *(const float4*)(Ab + (size_t)(m0 + row) * LSEQ + k0 + c4);
                float4 km = *(const float4*)(mkb + k0 + c4);
                float Mv = Ml[row], Rv = Rl[row];
                ushort4 w;
                w.x = (km.x != 0.f) ? f2bf(__expf(x.x - Mv) * Rv) : (unsigned short)0;
                w.y = (km.y != 0.f) ? f2bf(__expf(x.y - Mv) * Rv) : (unsigned short)0;
                w.z = (km.z != 0.f) ? f2bf(__expf(x.z - Mv) * Rv) : (unsigned short)0;
                w.w = (km.w != 0.f) ? f2bf(__expf(x.w - Mv) * Rv) : (unsigned short)0;
                *(ushort4*)&Wl[row * LDP + c4] = w;
            }
        } else {
#pragma unroll
            for (int r = 0; r < 4; ++r) {
                int mh = t & 127;
                int pq = (t >> 7) + (r << 1);
                float Mv = Ml[mh], Rv = Rl[mh];
                ushort4 w;
#pragma unroll
                for (int j = 0; j < 4; ++j) {
                    int k = k0 + (pq << 2) + j;
                    float x  = Ab[(size_t)k * LSEQ + m0 + mh];
                    float km = mkb[k];
                    ((unsigned short*)&w)[j] =
                        (km != 0.f) ? f2bf(__expf(x - Mv) * Rv) : (unsigned short)0;
                }
                *(ushort4*)&Wl[mh * LDP + (pq << 2)] = w;
            }
        }
#pragma unroll
        for (int r = 0; r < 4; ++r) {
            int d  = t & 127;
            int kq = (t >> 7) + (r << 1);
            bool valid = (n0 + d) < DDIM;
            ushort4 v;
#pragma unroll
            for (int j = 0; j < 4; ++j) {
                int k = k0 + (kq << 2) + j;
                float x = valid ? Bb[(size_t)k * DDIM + n0 + d] : 0.f;
                ((unsigned short*)&v)[j] = f2bf(x);
            }
            *(ushort4*)&Bl[d * LDP + (kq << 2)] = v;
        }
        __syncthreads();

        short8 af[4], bfr[4];
#pragma unroll
        for (int i = 0; i < 4; ++i) {
            af[i]  = *(const short8*)&Wl[(wm + (i << 4) + fr) * LDP + (fq << 3)];
            bfr[i] = *(const short8*)&Bl[(wn + (i << 4) + fr) * LDP + (fq << 3)];
        }
#pragma unroll
        for (int mi = 0; mi < 4; ++mi)
#pragma unroll
            for (int ni = 0; ni < 4; ++ni)
                acc[mi][ni] = mfma16(af[mi], bfr[ni], acc[mi][ni]);
        __syncthreads();
    }

#pragma unroll
    for (int mi = 0; mi < 4; ++mi)
#pragma unroll
        for (int j = 0; j < 4; ++j) {
            int row = wm + (mi << 4) + (fq << 2) + j;
            float mm = Mm[row];
#pragma unroll
            for (int ni = 0; ni < 4; ++ni) {
                int d = n0 + wn + (ni << 4) + fr;
                if (d < DDIM)
                    out[((size_t)(b << 9) + m0 + row) * DDIM + d] = mm * acc[mi][ni][j];
            }
        }
}

// ---------------------------------------------------------------------------
extern "C" void kernel_launch(void* const* d_in, const int* in_sizes, int n_in,
                              void* d_out, int out_size, void* d_ws, size_t ws_size,
                              hipStream_t stream)
{
    const float* P  = (const float*)d_in[0];   // encoded_premise   [64,512,600]
    const float* pm = (const float*)d_in[1];   // premise_mask      [64,512]
    const float* H  = (const float*)d_in[2];   // encoded_hypothesis[64,512,600]
    const float* hm = (const float*)d_in[3];   // hypothesis_mask   [64,512]
    float* out = (float*)d_out;
    char* ws = (char*)d_ws;

    const size_t E = (size_t)DEVB * LSEQ * DDIM;   // 19,660,800 out-elems per half

    // ws layout (fast path, 137,625,600 B needed — d_out no longer used as scratch):
    //   attn fp32 [0 : 67.11M) | W1 [67.11M : 100.66M) | W2 [100.66M : 134.22M)
    //   Mp/Tp/Sp [134.22M : 137.36M) | M1/R1 [137.36M : 137.63M)
    const size_t fast_need = 137625600;

    if (ws_size >= fast_need) {
        float*     attn = (float*)ws;
        _Float16*  W1   = (_Float16*)(ws + 67108864);
        _Float16*  W2   = (_Float16*)(ws + 67108864 + 33554432);
        float*     Mp   = (float*)(ws + 134217728);
        float*     Tp   = Mp + (size_t)DEVB * 8 * 512;
        float*     Sp   = Tp + (size_t)DEVB * 8 * 512;
        float*     M1   = Sp + (size_t)DEVB * 8 * 512;
        float*     R1   = M1 + DEVB * LSEQ;

        attn_gemm<<<DEVB * 16, 256, 0, stream>>>(P, H, attn);
        stats_w1<<<DEVB * 8, 256, 0, stream>>>(attn, hm, pm, M1, R1, W1, Mp, Tp, Sp);
        w2gen3<<<DEVB * 32, 256, 0, stream>>>(attn, pm, Mp, Tp, Sp, W2);
        gemm_dual<<<DEVB * 40, 256, 0, stream>>>(W1, W2, P, H, pm, hm, out);
    } else {
        // fallback: attn + partials + stats = 70.78 MB of ws
        float* attn = (float*)ws;
        float* Mp   = (float*)(ws + 67108864);
        float* Tp   = Mp + (size_t)DEVB * 8 * 512;
        float* Sp   = Tp + (size_t)DEVB * 8 * 512;
        float* M1   = Sp + (size_t)DEVB * 8 * 512;
        float* R1   = M1 + DEVB * LSEQ;
        float* M2   = R1 + DEVB * LSEQ;
        float* R2   = M2 + DEVB * LSEQ;

        attn_gemm<<<DEVB * 16, 256, 0, stream>>>(P, H, attn);
        stats_w1<<<DEVB * 8, 256, 0, stream>>>(attn, hm, pm, M1, R1, nullptr, Mp, Tp, Sp);
        col_merge<<<DEVB * 2, 256, 0, stream>>>(Mp, Tp, Sp, M2, R2);
        wsum<0><<<DEVB * 20, 256, 0, stream>>>(attn, H, hm, pm, M1, R1, out);
        wsum<1><<<DEVB * 20, 256, 0, stream>>>(attn, P, pm, hm, M2, R2, out + E);
    }
}

// Round 14
// 312.461 us; speedup vs baseline: 1.6763x; 1.0086x over previous
//
#include <hip/hip_runtime.h>
#include <hip/hip_bf16.h>

#define DEVB 64
#define LSEQ 512
#define DDIM 600

typedef short short8 __attribute__((ext_vector_type(8)));
typedef float f32x4 __attribute__((ext_vector_type(4)));
typedef _Float16 f16x8 __attribute__((ext_vector_type(8)));
typedef _Float16 f16x4 __attribute__((ext_vector_type(4)));

constexpr int LDP = 40;   // padded stride for fallback-wsum tiles (16B-aligned rows)

__device__ __forceinline__ unsigned short f2bf(float x) {
    union { float f; unsigned u; } v; v.f = x;
    unsigned r = v.u + 0x7fffu + ((v.u >> 16) & 1u);   // RNE
    return (unsigned short)(r >> 16);
}
__device__ __forceinline__ unsigned pk16(float a, float b) {
    union { _Float16 h[2]; unsigned u; } p;
    p.h[0] = (_Float16)a; p.h[1] = (_Float16)b;
    return p.u;
}
__device__ __forceinline__ f32x4 mfma16(short8 a, short8 b, f32x4 c) {
    return __builtin_amdgcn_mfma_f32_16x16x32_bf16(a, b, c, 0, 0, 0);
}
__device__ __forceinline__ f32x4 mfma16h(f16x8 a, f16x8 b, f32x4 c) {
    return __builtin_amdgcn_mfma_f32_16x16x32_f16(a, b, c, 0, 0, 0);
}

// ---------------------------------------------------------------------------
// K0: transcvt3 — XT[b][d][r] = fp16(X[b][r][d]) for X in {P, H}, one grid.
//     64r x 128d strip per block; u32-paired LDS writes. (proven R12)
// ---------------------------------------------------------------------------
__global__ __launch_bounds__(256) void transcvt3(
    const float* __restrict__ P, const float* __restrict__ H,
    _Float16* __restrict__ pT, _Float16* __restrict__ hT)
{
    int blk = blockIdx.x;
    const float* X; _Float16* XT;
    const int half = DEVB * 40;
    if (blk < half) { X = P; XT = pT; }
    else { blk -= half; X = H; XT = hT; }

    int b   = blk / 40;
    int rem = blk % 40;
    int r0  = (rem / 5) << 6;       // 8 r-tiles of 64
    int d0  = (rem % 5) << 7;       // 5 d-strips of 128
    const float* Xb = X + (size_t)b * LSEQ * DDIM;

    __shared__ unsigned T32[2][64 * 33];
    const int t  = threadIdx.x;
    const int rp = t >> 3;          // 0..31 row-pair
    const int dc = (t & 7) << 3;    // 0..56

#pragma unroll
    for (int ht_ = 0; ht_ < 2; ++ht_) {
        int dd = d0 + (ht_ << 6) + dc;
        if (dd < DDIM) {            // 8-chunks fully valid or invalid (600%8==0)
            const float* s0 = Xb + (size_t)(r0 + 2 * rp) * DDIM + dd;
            const float* s1 = s0 + DDIM;
            float4 a0 = *(const float4*)s0, a1 = *(const float4*)(s0 + 4);
            float4 b0 = *(const float4*)s1, b1 = *(const float4*)(s1 + 4);
            float xa[8] = {a0.x, a0.y, a0.z, a0.w, a1.x, a1.y, a1.z, a1.w};
            float xb[8] = {b0.x, b0.y, b0.z, b0.w, b1.x, b1.y, b1.z, b1.w};
#pragma unroll
            for (int j = 0; j < 8; ++j)
                T32[ht_][(dc + j) * 33 + rp] = pk16(xa[j], xb[j]);
        }
    }
    __syncthreads();

    const int dl = t >> 2;          // 0..63
    const int q  = t & 3;
#pragma unroll
    for (int ht_ = 0; ht_ < 2; ++ht_) {
        int d = d0 + (ht_ << 6) + dl;
        if (d < DDIM) {
            unsigned buf[8];
#pragma unroll
            for (int i = 0; i < 8; ++i)
                buf[i] = T32[ht_][dl * 33 + q * 8 + i];
            unsigned* dst = (unsigned*)(XT + ((size_t)b * DDIM + d) * LSEQ + r0) + q * 8;
            *(uint4*)(dst)     = *(uint4*)&buf[0];
            *(uint4*)(dst + 4) = *(uint4*)&buf[4];
        }
    }
}

// ---------------------------------------------------------------------------
// K1: attn[b][p][h] = sum_d P[b][p][d] * H[b][h][d]   (fp32 out)
// R9/R12 proven: 256 threads, 128x128, fp32 direct reads, hi/lo fp16 split in
// LDS-write phase, 48 KB dbuf, chunk-XOR swizzle (0 conflicts). No 2nd
// launch_bounds arg (R10: VGPR capped at 64 -> accumulator spill).
// ---------------------------------------------------------------------------
__global__ __launch_bounds__(256) void attn_gemm(
    const float* __restrict__ P, const float* __restrict__ H,
    float* __restrict__ attn)
{
    const int bid = blockIdx.x;
    const int swz = (bid & 7) * 128 + (bid >> 3);   // 1024 blocks, 8 XCDs
    const int b  = swz >> 4;
    const int pt = ((swz >> 2) & 3) << 7;
    const int ht = (swz & 3) << 7;
    const float* Pb = P + ((size_t)b * LSEQ + pt) * DDIM;
    const float* Hb = H + ((size_t)b * LSEQ + ht) * DDIM;
    float* Ab = attn + (size_t)b * LSEQ * LSEQ;

    __shared__ _Float16 Ah[2][128 * 32], Al[2][128 * 32], Bh[2][128 * 32];

    const int t    = threadIdx.x;
    const int lane = t & 63;
    const int wave = t >> 6;
    const int wm = (wave >> 1) << 6;
    const int wn = (wave & 1) << 6;
    const int fr = lane & 15;
    const int fq = lane >> 4;
    const int srow = t >> 2;          // 0..63 (r=1 adds 64)
    const int sc8  = (t & 3) << 3;    // logical col chunk base (8 elems)

    const int wchunk = (t & 3) ^ ((srow >> 1) & 3);
    const int woff   = srow * 32 + (wchunk << 3);          // + r*64*32
    const int rcoff  = ((fq ^ ((fr >> 1) & 3)) << 3);

    float4 pf[8];
    const float4 fz = {0.f, 0.f, 0.f, 0.f};
    auto issue = [&](int k0) {
        bool ok = (k0 + sc8) < DDIM;   // zero the 600..607 tail chunk
#pragma unroll
        for (int r = 0; r < 2; ++r) {
            size_t base = (size_t)(srow + (r << 6)) * DDIM + k0 + sc8;
            if (ok) {
                pf[r * 4 + 0] = *(const float4*)(Pb + base);
                pf[r * 4 + 1] = *(const float4*)(Pb + base + 4);
                pf[r * 4 + 2] = *(const float4*)(Hb + base);
                pf[r * 4 + 3] = *(const float4*)(Hb + base + 4);
            } else {
                pf[r * 4 + 0] = fz; pf[r * 4 + 1] = fz;
                pf[r * 4 + 2] = fz; pf[r * 4 + 3] = fz;
            }
        }
    };
    auto wr = [&](int buf) {
#pragma unroll
        for (int r = 0; r < 2; ++r) {
            float4 a0 = pf[r * 4 + 0], a1 = pf[r * 4 + 1];
            float4 h0 = pf[r * 4 + 2], h1 = pf[r * 4 + 3];
            float af[8] = {a0.x, a0.y, a0.z, a0.w, a1.x, a1.y, a1.z, a1.w};
            float hf[8] = {h0.x, h0.y, h0.z, h0.w, h1.x, h1.y, h1.z, h1.w};
            f16x8 hi, lo, bh;
#pragma unroll
            for (int j = 0; j < 8; ++j) {
                hi[j] = (_Float16)af[j];
                lo[j] = (_Float16)(af[j] - (float)hi[j]);
                bh[j] = (_Float16)hf[j];
            }
            int off = woff + (r << 11);                    // r*64*32
            *(f16x8*)&Ah[buf][off] = hi;
            *(f16x8*)&Al[buf][off] = lo;
            *(f16x8*)&Bh[buf][off] = bh;
        }
    };

    issue(0);
    wr(0);
    issue(32);
    __syncthreads();

    f32x4 acc[4][4];
#pragma unroll
    for (int i = 0; i < 4; ++i)
#pragma unroll
        for (int j = 0; j < 4; ++j) acc[i][j] = (f32x4){0.f, 0.f, 0.f, 0.f};

    constexpr int NK = 19;   // ceil(600/32)
    int cur = 0;
    for (int it = 0; it < NK; ++it) {
        f16x8 ah[4], al[4], bh[4];
#pragma unroll
        for (int i = 0; i < 4; ++i) {
            int ra = (wm + (i << 4) + fr) * 32 + rcoff;
            int rb = (wn + (i << 4) + fr) * 32 + rcoff;
            ah[i] = *(const f16x8*)&Ah[cur][ra];
            al[i] = *(const f16x8*)&Al[cur][ra];
            bh[i] = *(const f16x8*)&Bh[cur][rb];
        }
        if (it + 1 < NK) {
            wr(cur ^ 1);                       // cvt + stage tile it+1
            if (it + 2 < NK) issue((it + 2) << 5);
        }
#pragma unroll
        for (int mi = 0; mi < 4; ++mi)
#pragma unroll
            for (int ni = 0; ni < 4; ++ni) {
                f32x4 c = acc[mi][ni];
                c = mfma16h(ah[mi], bh[ni], c);
                c = mfma16h(al[mi], bh[ni], c);
                acc[mi][ni] = c;
            }
        __syncthreads();
        cur ^= 1;
    }

#pragma unroll
    for (int mi = 0; mi < 4; ++mi)
#pragma unroll
        for (int ni = 0; ni < 4; ++ni)
#pragma unroll
            for (int j = 0; j < 4; ++j) {
                int p = pt + wm + (mi << 4) + (fq << 2) + j;
                int h = ht + wn + (ni << 4) + fr;
                Ab[(size_t)p * LSEQ + h] = acc[mi][ni][j];
            }
}

// ---------------------------------------------------------------------------
// K2: stats_w1 — ONE pass over attn per 64-row stripe:
//   per-row (over h): M1, R1, W1 fp16 (hm-masked softmax)
//   per-col partials (over p, pm-masked online): Mp/Tp/Sp [b][8][512]
// ---------------------------------------------------------------------------
__global__ __launch_bounds__(256) void stats_w1(
    const float* __restrict__ attn, const float* __restrict__ hmask,
    const float* __restrict__ pmask,
    float* __restrict__ M1, float* __restrict__ R1,
    _Float16* __restrict__ W1,
    float* __restrict__ Mp, float* __restrict__ Tp, float* __restrict__ Sp)
{
    int b      = blockIdx.x >> 3;
    int stripe = blockIdx.x & 7;
    int lane   = threadIdx.x & 63;
    int wave   = threadIdx.x >> 6;
    const float* hm = hmask + (b << 9);
    const float* pm = pmask + (b << 9);

    float4 m0 = *(const float4*)(hm + (lane << 3));
    float4 m1 = *(const float4*)(hm + (lane << 3) + 4);
    float mk[8] = {m0.x, m0.y, m0.z, m0.w, m1.x, m1.y, m1.z, m1.w};

    float cM[8], cT[8], cS[8];
#pragma unroll
    for (int j = 0; j < 8; ++j) { cM[j] = -1e30f; cT[j] = 0.f; cS[j] = 0.f; }

    for (int i = 0; i < 16; ++i) {
        int row   = (stripe << 6) + (wave << 4) + i;
        int rowid = (b << 9) + row;
        const float* rp = attn + (size_t)rowid * LSEQ + (lane << 3);
        float4 s0 = *(const float4*)rp;
        float4 s1 = *(const float4*)(rp + 4);
        float s[8] = {s0.x, s0.y, s0.z, s0.w, s1.x, s1.y, s1.z, s1.w};

        float v[8];
#pragma unroll
        for (int j = 0; j < 8; ++j) v[j] = s[j] * mk[j];
        float mx = -1e30f;
#pragma unroll
        for (int j = 0; j < 8; ++j) mx = fmaxf(mx, v[j]);
#pragma unroll
        for (int off = 32; off; off >>= 1) mx = fmaxf(mx, __shfl_xor(mx, off));

        float e[8], T = 0.f, S = 0.f;
#pragma unroll
        for (int j = 0; j < 8; ++j) { e[j] = __expf(v[j] - mx); T += mk[j] * e[j]; S += e[j]; }
#pragma unroll
        for (int off = 32; off; off >>= 1) { T += __shfl_xor(T, off); S += __shfl_xor(S, off); }
        float R = 1.f / (T + 1e-13f * S);

        if (W1) {
            union { f16x8 v8; _Float16 h[8]; } wv;
#pragma unroll
            for (int j = 0; j < 8; ++j) wv.h[j] = (_Float16)(mk[j] * e[j] * R);
            *(f16x8*)(W1 + (size_t)rowid * LSEQ + (lane << 3)) = wv.v8;
        }
        if (lane == 0) { M1[rowid] = mx; R1[rowid] = R; }

        float pmv = pm[row];
#pragma unroll
        for (int j = 0; j < 8; ++j) {
            float v2 = s[j] * pmv;
            float nm = fmaxf(cM[j], v2);
            float sc = __expf(cM[j] - nm);
            float e2 = __expf(v2 - nm);
            cT[j] = cT[j] * sc + pmv * e2;
            cS[j] = cS[j] * sc + e2;
            cM[j] = nm;
        }
    }

    __shared__ float LM[4][512], LT[4][512], LS[4][512];
#pragma unroll
    for (int j = 0; j < 8; ++j) {
        int c = (lane << 3) + j;
        LM[wave][c] = cM[j]; LT[wave][c] = cT[j]; LS[wave][c] = cS[j];
    }
    __syncthreads();

    size_t base = (size_t)((b << 3) + stripe) * 512;
    for (int cc = threadIdx.x; cc < 512; cc += 256) {
        float gm = fmaxf(fmaxf(LM[0][cc], LM[1][cc]), fmaxf(LM[2][cc], LM[3][cc]));
        float gT = 0.f, gS = 0.f;
#pragma unroll
        for (int w = 0; w < 4; ++w) {
            float sc = __expf(LM[w][cc] - gm);
            gT += LT[w][cc] * sc;
            gS += LS[w][cc] * sc;
        }
        Mp[base + cc] = gm; Tp[base + cc] = gT; Sp[base + cc] = gS;
    }
}

// ---------------------------------------------------------------------------
// K3 (fallback only): col_merge — merge 8 stripe partials -> M2, R2
// ---------------------------------------------------------------------------
__global__ __launch_bounds__(256) void col_merge(
    const float* __restrict__ Mp, const float* __restrict__ Tp,
    const float* __restrict__ Sp, float* __restrict__ M2, float* __restrict__ R2)
{
    int b = blockIdx.x >> 1;
    int c = ((blockIdx.x & 1) << 8) + threadIdx.x;
    float gm = -1e30f, gT = 0.f, gS = 0.f;
#pragma unroll
    for (int st = 0; st < 8; ++st) {
        size_t idx = (size_t)((b << 3) + st) * 512 + c;
        float m = Mp[idx], tt = Tp[idx], ss = Sp[idx];
        float nm  = fmaxf(gm, m);
        float sc1 = __expf(gm - nm), sc2 = __expf(m - nm);
        gT = gT * sc1 + tt * sc2;
        gS = gS * sc1 + ss * sc2;
        gm = nm;
    }
    M2[(b << 9) + c] = gm;
    R2[(b << 9) + c] = 1.f / (gT + 1e-13f * gS);
}

// ---------------------------------------------------------------------------
// K4: w2gen3 — per-block 8-stripe merge then W2[b][h][p] fp16 via u32-paired
//     LDS transpose (proven R12). Tile = 64p x 128h.
// ---------------------------------------------------------------------------
__global__ __launch_bounds__(256) void w2gen3(
    const float* __restrict__ attn, const float* __restrict__ pmask,
    const float* __restrict__ Mp, const float* __restrict__ Tp,
    const float* __restrict__ Sp, _Float16* __restrict__ W2)
{
    int blk = blockIdx.x;
    int b  = blk >> 5;
    int p0 = ((blk >> 2) & 7) << 6;
    int h0 = (blk & 3) << 7;
    const float* Ab = attn + (size_t)b * LSEQ * LSEQ;
    const float* pm = pmask + (b << 9);

    __shared__ float sM[128], sR[128];
    __shared__ unsigned T32[128 * 33];
    const int t = threadIdx.x;
    if (t < 128) {
        float gm = -1e30f, gT = 0.f, gS = 0.f;
#pragma unroll
        for (int st = 0; st < 8; ++st) {
            size_t idx = (size_t)((b << 3) + st) * 512 + h0 + t;
            float m = Mp[idx], tt = Tp[idx], ss = Sp[idx];
            float nm  = fmaxf(gm, m);
            float sc1 = __expf(gm - nm), sc2 = __expf(m - nm);
            gT = gT * sc1 + tt * sc2;
            gS = gS * sc1 + ss * sc2;
            gm = nm;
        }
        sM[t] = gm;
        sR[t] = 1.f / (gT + 1e-13f * gS);
    }
    __syncthreads();

#pragma unroll
    for (int it = 0; it < 4; ++it) {
        int g  = t + (it << 8);
        int pp = g >> 5;           // 0..31 p-pair
        int hc = (g & 31) << 2;    // 0..124
        const float* s0 = Ab + (size_t)(p0 + 2 * pp) * LSEQ + h0 + hc;
        float4 xa = *(const float4*)s0;
        float4 xb = *(const float4*)(s0 + LSEQ);
        float pa = pm[p0 + 2 * pp];
        float pb = pm[p0 + 2 * pp + 1];
        float a[4] = {xa.x, xa.y, xa.z, xa.w};
        float bb[4] = {xb.x, xb.y, xb.z, xb.w};
#pragma unroll
        for (int j = 0; j < 4; ++j) {
            float wa = (pa != 0.f) ? __expf(a[j]  - sM[hc + j]) * sR[hc + j] : 0.f;
            float wb = (pb != 0.f) ? __expf(bb[j] - sM[hc + j]) * sR[hc + j] : 0.f;
            T32[(hc + j) * 33 + pp] = pk16(wa, wb);
        }
    }
    __syncthreads();

    const int hl = t >> 1;          // 0..127
    const int q  = t & 1;
    unsigned buf[16];
#pragma unroll
    for (int i = 0; i < 16; ++i)
        buf[i] = T32[hl * 33 + q * 16 + i];
    unsigned* dst = (unsigned*)(W2 + ((size_t)(b << 9) + h0 + hl) * LSEQ + p0) + q * 16;
#pragma unroll
    for (int i = 0; i < 4; ++i)
        *(uint4*)(dst + 4 * i) = *(uint4*)&buf[4 * i];
}

// ---------------------------------------------------------------------------
// K5: gemm64 — out[b][m][d] = mask_m[m] * sum_k W[b][m][k] * BT[b][d][k]
//     BK=64 double-buffered: 8 K-steps, ONE barrier each (half of BK=32),
//     32 MFMA per step. LDS [128][64] x2 ops x2 buf = 64 KB -> 2 blocks/CU.
//     XOR swizzle keyed on row&7 (row stride 32 u32 == 0 mod 32 banks):
//     reads 2-way free, writes at throughput floor.
// ---------------------------------------------------------------------------
__global__ __launch_bounds__(256) void gemm64(
    const _Float16* __restrict__ W, const _Float16* __restrict__ BT,
    const float* __restrict__ mask_m, float* __restrict__ out)
{
    const int bid = blockIdx.x;
    const int swz = (bid & 7) * 160 + (bid >> 3);   // 1280 blocks, 8 XCDs
    const int b   = swz / 20;
    const int rem = swz % 20;
    const int m0  = (rem / 5) << 7;
    const int n0  = (rem % 5) << 7;
    const _Float16* Wb = W  + (size_t)b * LSEQ * LSEQ;
    const _Float16* Bb = BT + (size_t)b * DDIM * LSEQ;

    __shared__ _Float16 Wl[2][128 * 64];
    __shared__ _Float16 Bl[2][128 * 64];

    const int t    = threadIdx.x;
    const int lane = t & 63;
    const int wave = t >> 6;
    const int wm = (wave >> 1) << 6;
    const int wn = (wave & 1) << 6;
    const int fr = lane & 15;
    const int fq = lane >> 4;

    // staging: 128 rows x 64 cols / 256 threads = 4 rows of one 8-chunk each
    const int srow = t >> 3;                  // 0..31 (+32 per r)
    const int sc8  = (t & 7) << 3;            // 0..56
    // write: physical chunk = logical ^ (row&7); row&7 == srow&7 (r*32 = 0 mod 8)
    const int woff = srow * 64 + ((((t & 7) ^ (srow & 7))) << 3);
    // read: row&7 == fr&7; logical chunk = fq + 4*half
    const int rc0 = ((fq      ^ (fr & 7)) << 3);
    const int rc1 = (((fq + 4) ^ (fr & 7)) << 3);

    f16x8 pw[4], pb[4];
    const f16x8 zz = {0, 0, 0, 0, 0, 0, 0, 0};
    auto issue = [&](int k0) {
#pragma unroll
        for (int r = 0; r < 4; ++r) {
            int row = srow + (r << 5);
            pw[r] = *(const f16x8*)(Wb + (size_t)(m0 + row) * LSEQ + k0 + sc8);
            int nrow = n0 + row;
            pb[r] = (nrow < DDIM) ? *(const f16x8*)(Bb + (size_t)nrow * LSEQ + k0 + sc8) : zz;
        }
    };
    auto wr = [&](int buf) {
#pragma unroll
        for (int r = 0; r < 4; ++r) {
            int off = woff + (r << 11);       // r*32*64
            *(f16x8*)&Wl[buf][off] = pw[r];
            *(f16x8*)&Bl[buf][off] = pb[r];
        }
    };

    issue(0);
    wr(0);
    issue(64);
    __syncthreads();

    f32x4 acc[4][4];
#pragma unroll
    for (int i = 0; i < 4; ++i)
#pragma unroll
        for (int j = 0; j < 4; ++j) acc[i][j] = (f32x4){0.f, 0.f, 0.f, 0.f};

    constexpr int NK = 8;   // 512/64
    int cur = 0;
    for (int it = 0; it < NK; ++it) {
        // ---- half 0 (k = 0..31 of this 64-tile)
        f16x8 af[4], bf0[4];
#pragma unroll
        for (int i = 0; i < 4; ++i) {
            af[i]  = *(const f16x8*)&Wl[cur][(wm + (i << 4) + fr) * 64 + rc0];
            bf0[i] = *(const f16x8*)&Bl[cur][(wn + (i << 4) + fr) * 64 + rc0];
        }
        if (it + 1 < NK) {
            wr(cur ^ 1);                       // stage tile it+1 into other buffer
            if (it + 2 < NK) issue((it + 2) << 6);
        }
#pragma unroll
        for (int mi = 0; mi < 4; ++mi)
#pragma unroll
            for (int ni = 0; ni < 4; ++ni)
                acc[mi][ni] = mfma16h(af[mi], bf0[ni], acc[mi][ni]);
        // ---- half 1 (k = 32..63)
        f16x8 ag[4], bf1[4];
#pragma unroll
        for (int i = 0; i < 4; ++i) {
            ag[i]  = *(const f16x8*)&Wl[cur][(wm + (i << 4) + fr) * 64 + rc1];
            bf1[i] = *(const f16x8*)&Bl[cur][(wn + (i << 4) + fr) * 64 + rc1];
        }
#pragma unroll
        for (int mi = 0; mi < 4; ++mi)
#pragma unroll
            for (int ni = 0; ni < 4; ++ni)
                acc[mi][ni] = mfma16h(ag[mi], bf1[ni], acc[mi][ni]);
        __syncthreads();
        cur ^= 1;
    }

    const float* mmb = mask_m + (b << 9) + m0;
#pragma unroll
    for (int mi = 0; mi < 4; ++mi)
#pragma unroll
        for (int j = 0; j < 4; ++j) {
            int row = wm + (mi << 4) + (fq << 2) + j;
            float mm = mmb[row];
#pragma unroll
            for (int ni = 0; ni < 4; ++ni) {
                int d = n0 + wn + (ni << 4) + fr;
                if (d < DDIM)
                    out[((size_t)(b << 9) + m0 + row) * DDIM + d] = mm * acc[mi][ni][j];
            }
        }
}

// ---------------------------------------------------------------------------
// Fallback wsum (round-1 style) — only if ws_size too small for fast path
// ---------------------------------------------------------------------------
template <int TRANSA>
__global__ __launch_bounds__(256) void wsum(
    const float* __restrict__ attn, const float* __restrict__ Bsrc,
    const float* __restrict__ mask_k, const float* __restrict__ mask_m,
    const float* __restrict__ Mst, const float* __restrict__ Rst,
    float* __restrict__ out)
{
    const int blk = blockIdx.x;
    const int b   = blk / 20;
    const int rem = blk % 20;
    const int m0  = (rem / 5) << 7;
    const int n0  = (rem % 5) << 7;

    const float* Ab  = attn + (size_t)b * LSEQ * LSEQ;
    const float* Bb  = Bsrc + (size_t)b * LSEQ * DDIM;
    const float* mkb = mask_k + (b << 9);

    __shared__ unsigned short Wl[128 * LDP];
    __shared__ unsigned short Bl[128 * LDP];
    __shared__ float Ml[128], Rl[128], Mm[128];

    const int t    = threadIdx.x;
    const int lane = t & 63;
    const int wave = t >> 6;
    const int wm = (wave >> 1) << 6;
    const int wn = (wave & 1) << 6;
    const int fr = lane & 15;
    const int fq = lane >> 4;

    if (t < 128) {
        Ml[t] = Mst[(b << 9) + m0 + t];
        Rl[t] = Rst[(b << 9) + m0 + t];
        Mm[t] = mask_m[(b << 9) + m0 + t];
    }
    __syncthreads();

    f32x4 acc[4][4];
#pragma unroll
    for (int i = 0; i < 4; ++i)
#pragma unroll
        for (int j = 0; j < 4; ++j) acc[i][j] = (f32x4){0.f, 0.f, 0.f, 0.f};

    for (int k0 = 0; k0 < LSEQ; k0 += 32) {
        if constexpr (TRANSA == 0) {
#pragma unroll
            for (int r = 0; r < 4; ++r) {
                int idx = t + (r << 8);
                int row = idx >> 3;
                int c4  = (idx & 7) << 2;
                float4 x  = *(const float4*)(Ab + (size_t)(m0 + row) * LSEQ + k0 + c4);
                float4 km = *(const float4*)(mkb + k0 + c4);
                float Mv = Ml[row], Rv = Rl[row];
                ushort4 w;
                w.x = (km.x != 0.f) ? f2bf(__expf(x.x - Mv) * Rv) : (unsigned short)0;
                w.y = (km.y != 0.f) ? f2bf(__expf(x.y - Mv) * Rv) : (unsigned short)0;
                w.z = (km.z != 0.f) ? f2bf(__expf(x.z - Mv) * Rv) : (unsigned short)0;
                w.w = (km.w != 0.f) ? f2bf(__expf(x.w - Mv) * Rv) : (unsigned short)0;
                *(ushort4*)&Wl[row * LDP + c4] = w;
            }
        } else {
#pragma unroll
            for (int r = 0; r < 4; ++r) {
                int mh = t & 127;
                int pq = (t >> 7) + (r << 1);
                float Mv = Ml[mh], Rv = Rl[mh];
                ushort4 w;
#pragma unroll
                for (int j = 0; j < 4; ++j) {
                    int k = k0 + (pq << 2) + j;
                    float x  = Ab[(size_t)k * LSEQ + m0 + mh];
                    float km = mkb[k];
                    ((unsigned short*)&w)[j] =
                        (km != 0.f) ? f2bf(__expf(x - Mv) * Rv) : (unsigned short)0;
                }
                *(ushort4*)&Wl[mh * LDP + (pq << 2)] = w;
            }
        }
#pragma unroll
        for (int r = 0; r < 4; ++r) {
            int d  = t & 127;
            int kq = (t >> 7) + (r << 1);
            bool valid = (n0 + d) < DDIM;
            ushort4 v;
#pragma unroll
            for (int j = 0; j < 4; ++j) {
                int k = k0 + (kq << 2) + j;
                float x = valid ? Bb[(size_t)k * DDIM + n0 + d] : 0.f;
                ((unsigned short*)&v)[j] = f2bf(x);
            }
            *(ushort4*)&Bl[d * LDP + (kq << 2)] = v;
        }
        __syncthreads();

        short8 af[4], bfr[4];
#pragma unroll
        for (int i = 0; i < 4; ++i) {
            af[i]  = *(const short8*)&Wl[(wm + (i << 4) + fr) * LDP + (fq << 3)];
            bfr[i] = *(const short8*)&Bl[(wn + (i << 4) + fr) * LDP + (fq << 3)];
        }
#pragma unroll
        for (int mi = 0; mi < 4; ++mi)
#pragma unroll
            for (int ni = 0; ni < 4; ++ni)
                acc[mi][ni] = mfma16(af[mi], bfr[ni], acc[mi][ni]);
        __syncthreads();
    }

#pragma unroll
    for (int mi = 0; mi < 4; ++mi)
#pragma unroll
        for (int j = 0; j < 4; ++j) {
            int row = wm + (mi << 4) + (fq << 2) + j;
            float mm = Mm[row];
#pragma unroll
            for (int ni = 0; ni < 4; ++ni) {
                int d = n0 + wn + (ni << 4) + fr;
                if (d < DDIM)
                    out[((size_t)(b << 9) + m0 + row) * DDIM + d] = mm * acc[mi][ni][j];
            }
        }
}

// ---------------------------------------------------------------------------
extern "C" void kernel_launch(void* const* d_in, const int* in_sizes, int n_in,
                              void* d_out, int out_size, void* d_ws, size_t ws_size,
                              hipStream_t stream)
{
    const float* P  = (const float*)d_in[0];   // encoded_premise   [64,512,600]
    const float* pm = (const float*)d_in[1];   // premise_mask      [64,512]
    const float* H  = (const float*)d_in[2];   // encoded_hypothesis[64,512,600]
    const float* hm = (const float*)d_in[3];   // hypothesis_mask   [64,512]
    float* out = (float*)d_out;
    char* o  = (char*)d_out;
    char* ws = (char*)d_ws;

    const size_t E = (size_t)DEVB * LSEQ * DDIM;   // 19,660,800 out-elems per half

    // d_out scratch layout (proven R12; dispatches serialize on the stream):
    //   hT [78,643,200 : 117,964,800) fp16 | W1 [117,964,800 : 151,519,232) fp16
    //   gemm<0> writes out[0 : 78.6M) while reading hT/W1 — disjoint.
    //   gemm<1> writes out[78.6M : 157.3M) reading only ws (W2/pT) — hT/W1 dead.
    _Float16* hT = (_Float16*)(o + 78643200);
    _Float16* W1 = (_Float16*)(o + 117964800);

    // ws layout (fast path, proven R12):
    //   attn fp32 [0 : 67.11M) | pT [67.11 : 106.43M) | W2 [106.43 : 139.98M)
    //   Mp/Tp/Sp [139.98 : 143.13M) | M1/R1 [143.13 : 143.65M)
    const size_t fast_need = 143654912;

    if (ws_size >= fast_need) {
        float*     attn = (float*)ws;
        _Float16*  pT   = (_Float16*)(ws + 67108864);
        _Float16*  W2   = (_Float16*)(ws + 67108864 + 39321600);
        float*     Mp   = (float*)(ws + 139984896);
        float*     Tp   = Mp + (size_t)DEVB * 8 * 512;
        float*     Sp   = Tp + (size_t)DEVB * 8 * 512;
        float*     M1   = Sp + (size_t)DEVB * 8 * 512;
        float*     R1   = M1 + DEVB * LSEQ;

        transcvt3<<<DEVB * 80, 256, 0, stream>>>(P, H, pT, hT);
        attn_gemm<<<DEVB * 16, 256, 0, stream>>>(P, H, attn);
        stats_w1<<<DEVB * 8, 256, 0, stream>>>(attn, hm, pm, M1, R1, W1, Mp, Tp, Sp);
        w2gen3<<<DEVB * 32, 256, 0, stream>>>(attn, pm, Mp, Tp, Sp, W2);
        gemm64<<<DEVB * 20, 256, 0, stream>>>(W1, hT, pm, out);
        gemm64<<<DEVB * 20, 256, 0, stream>>>(W2, pT, hm, out + E);
    } else {
        // fallback: attn + partials + stats = 70.78 MB of ws; no prep needed
        float* attn = (float*)ws;
        float* Mp   = (float*)(ws + 67108864);
        float* Tp   = Mp + (size_t)DEVB * 8 * 512;
        float* Sp   = Tp + (size_t)DEVB * 8 * 512;
        float* M1   = Sp + (size_t)DEVB * 8 * 512;
        float* R1   = M1 + DEVB * LSEQ;
        float* M2   = R1 + DEVB * LSEQ;
        float* R2   = M2 + DEVB * LSEQ;

        attn_gemm<<<DEVB * 16, 256, 0, stream>>>(P, H, attn);
        stats_w1<<<DEVB * 8, 256, 0, stream>>>(attn, hm, pm, M1, R1, nullptr, Mp, Tp, Sp);
        col_merge<<<DEVB * 2, 256, 0, stream>>>(Mp, Tp, Sp, M2, R2);
        wsum<0><<<DEVB * 20, 256, 0, stream>>>(attn, H, hm, pm, M1, R1, out);
        wsum<1><<<DEVB * 20, 256, 0, stream>>>(attn, P, pm, hm, M2, R2, out + E);
    }
}